// Round 9
// baseline (324.660 us; speedup 1.0000x reference)
//
#include <hip/hip_runtime.h>

#define N_NODES 100000
#define N_EDGES 3200000
#define D_FEAT  512
#define HIDDEN  16
#define NCLS    6
#define BSH     7                      // bucket = col >> 7
#define BNODES  128                    // nodes per bucket
#define NBUK    782                    // ceil(N_NODES/128)
#define BCAP    6144                   // LDS bucket capacity (avg 4092, +32 sigma)
#define NBLK_A  512                    // build blocks: exactly 2 per CU
#define TILE    6250                   // ceil(N_EDGES/NBLK_A)

// ---------- helpers ----------

__device__ __forceinline__ int eidx(const int* __restrict__ ei, int is64, int pos) {
    return is64 ? ei[2 * (long long)pos] : ei[pos];
}

__global__ void k_detect(const int* __restrict__ ei, int* __restrict__ flag) {
    int v = ei[2 * threadIdx.x + 1];
    unsigned long long b = __ballot(v != 0);
    if (threadIdx.x == 0) flag[0] = (b == 0ULL) ? 1 : 0;
}

__device__ __forceinline__ unsigned short f2bf(float f) {     // RNE f32->bf16
    unsigned u = __float_as_uint(f);
    return (unsigned short)((u + 0x7FFFu + ((u >> 16) & 1u)) >> 16);
}

// ---------- bucket build ----------

__global__ __launch_bounds__(256)
void k_bhist(const int* __restrict__ ei, const int* __restrict__ flag,
             int* __restrict__ bcnt) {
    __shared__ int lh[NBUK];
    for (int i = threadIdx.x; i < NBUK; i += 256) lh[i] = 0;
    __syncthreads();
    int is64 = flag[0];
    int s = blockIdx.x * TILE, e1 = min(s + TILE, N_EDGES);
    for (int e = s + threadIdx.x; e < e1; e += 256) {
        int c = eidx(ei, is64, N_EDGES + e);
        atomicAdd(&lh[c >> BSH], 1);
    }
    __syncthreads();
    for (int i = threadIdx.x; i < NBUK; i += 256)
        if (lh[i]) atomicAdd(&bcnt[i], lh[i]);
}

__global__ void k_bscan(const int* __restrict__ bcnt, int* __restrict__ bstart,
                        int* __restrict__ bcursor) {
    __shared__ int s[1024];
    int t = threadIdx.x;
    int v = (t < NBUK) ? bcnt[t] : 0;
    s[t] = v;
    __syncthreads();
    for (int off = 1; off < 1024; off <<= 1) {
        int u = (t >= off) ? s[t - off] : 0;
        __syncthreads();
        s[t] += u;
        __syncthreads();
    }
    int excl = s[t] - v;
    if (t <= NBUK) bstart[t] = excl;
    if (t < NBUK)  bcursor[t] = excl;
}

// scatter edges into bucket-major abuf with block-reserved runs
// pack: x = row | (col&127)<<17  (row < 2^17), y = bits(w)
__global__ __launch_bounds__(256)
void k_bscat(const int* __restrict__ ei, const float* __restrict__ ew,
             const int* __restrict__ flag, int* __restrict__ bcursor,
             uint2* __restrict__ abuf) {
    __shared__ int lh[NBUK];
    __shared__ int lbase[NBUK];
    __shared__ int lcur[NBUK];
    for (int i = threadIdx.x; i < NBUK; i += 256) { lh[i] = 0; lcur[i] = 0; }
    __syncthreads();
    int is64 = flag[0];
    int s = blockIdx.x * TILE, e1 = min(s + TILE, N_EDGES);
    for (int e = s + threadIdx.x; e < e1; e += 256) {
        int c = eidx(ei, is64, N_EDGES + e);
        atomicAdd(&lh[c >> BSH], 1);
    }
    __syncthreads();
    for (int i = threadIdx.x; i < NBUK; i += 256)
        if (lh[i]) lbase[i] = atomicAdd(&bcursor[i], lh[i]);
    __syncthreads();
    for (int e = s + threadIdx.x; e < e1; e += 256) {
        int r = eidx(ei, is64, e);
        int c = eidx(ei, is64, N_EDGES + e);
        float w = ew[e];
        int b = c >> BSH;
        int off = atomicAdd(&lcur[b], 1);
        abuf[lbase[b] + off] = make_uint2((unsigned)r | ((unsigned)(c & (BNODES - 1)) << 17),
                                          __float_as_uint(w));
    }
}

// per-bucket counting sort (LDS-staged): abuf -> eperm {row, raw w};
// emits startA and dinv (cnt+wsum fused, single abuf read).
__global__ __launch_bounds__(256)
void k_bsort(const int* __restrict__ bstart, const uint2* __restrict__ abuf,
             uint2* __restrict__ eperm, int* __restrict__ startA,
             float* __restrict__ dinv) {
    __shared__ uint2 se[BCAP];                     // 48 KB
    __shared__ int   cnt[BNODES];
    __shared__ int   scn[256];
    __shared__ int   cur[BNODES];
    __shared__ float wsum[BNODES];
    int t = threadIdx.x, b = blockIdx.x;
    int s0 = bstart[b], s1 = bstart[b + 1];
    int nb = s1 - s0;
    if (t < BNODES) { cnt[t] = 0; wsum[t] = 0.0f; }
    __syncthreads();

    bool fits = (nb <= BCAP);
    if (fits) {
        for (int k = t; k < nb; k += 256) {
            uint2 a = abuf[s0 + k];
            se[k] = a;
            int ln = (int)(a.x >> 17);
            atomicAdd(&cnt[ln], 1);
            atomicAdd(&wsum[ln], __uint_as_float(a.y));
        }
    } else {
        for (int k = t; k < nb; k += 256) {
            uint2 a = abuf[s0 + k];
            int ln = (int)(a.x >> 17);
            atomicAdd(&cnt[ln], 1);
            atomicAdd(&wsum[ln], __uint_as_float(a.y));
        }
    }
    __syncthreads();
    int v = (t < BNODES) ? cnt[t] : 0;
    scn[t] = v;
    __syncthreads();
    for (int off = 1; off < 256; off <<= 1) {
        int u = (t >= off) ? scn[t - off] : 0;
        __syncthreads();
        scn[t] += u;
        __syncthreads();
    }
    int excl = scn[t] - v;
    if (t < BNODES) {
        cur[t] = excl;
        int node = b * BNODES + t;
        if (node <= N_NODES) startA[node] = s0 + excl;
        if (node <  N_NODES) dinv[node] = rsqrtf(1.0f + wsum[t]);
    }
    __syncthreads();
    if (fits) {
        for (int k = t; k < nb; k += 256) {
            uint2 a = se[k];
            int ln = (int)(a.x >> 17);
            int off = atomicAdd(&cur[ln], 1);
            eperm[s0 + off] = make_uint2(a.x & 0x1FFFFu, a.y);
        }
    } else {
        for (int k = t; k < nb; k += 256) {
            uint2 a = abuf[s0 + k];
            int ln = (int)(a.x >> 17);
            int off = atomicAdd(&cur[ln], 1);
            eperm[s0 + off] = make_uint2(a.x & 0x1FFFFu, a.y);
        }
    }
}

// ---------- layer 1 transform: h1 = x @ W1 (bf16 output, 32B rows) ----------
// 128 rows/block x 782 blocks. x tile transposed in LDS (pad 129).

__global__ __launch_bounds__(128)
void k_gemm1(const float* __restrict__ x, const float* __restrict__ W1g,
             unsigned short* __restrict__ h1b) {
    __shared__ float xT[32 * 129];          // 16.5 KB
    const int t = threadIdx.x;
    const int row0 = blockIdx.x * 128;
    const int myrow = row0 + t;

    float4 rg[8], rn[8];
#pragma unroll
    for (int p = 0; p < 8; ++p) {
        int f = t + 128 * p;
        int lr = f >> 3, lc = f & 7;
        int gr = min(row0 + lr, N_NODES - 1);
        rg[p] = *(const float4*)(x + (size_t)gr * D_FEAT + 4 * lc);
    }

    float acc[16];
#pragma unroll
    for (int j = 0; j < 16; ++j) acc[j] = 0.0f;

    for (int ch = 0; ch < 16; ++ch) {
        __syncthreads();
#pragma unroll
        for (int p = 0; p < 8; ++p) {
            int f = t + 128 * p;
            int lr = f >> 3, lc = f & 7;
            xT[(4 * lc + 0) * 129 + lr] = rg[p].x;
            xT[(4 * lc + 1) * 129 + lr] = rg[p].y;
            xT[(4 * lc + 2) * 129 + lr] = rg[p].z;
            xT[(4 * lc + 3) * 129 + lr] = rg[p].w;
        }
        if (ch < 15) {
            int k0n = (ch + 1) * 32;
#pragma unroll
            for (int p = 0; p < 8; ++p) {
                int f = t + 128 * p;
                int lr = f >> 3, lc = f & 7;
                int gr = min(row0 + lr, N_NODES - 1);
                rn[p] = *(const float4*)(x + (size_t)gr * D_FEAT + k0n + 4 * lc);
            }
        }
        __syncthreads();
        const int k0 = ch * 32;
#pragma unroll
        for (int k = 0; k < 32; ++k) {
            float xk = xT[k * 129 + t];
            const float* wr = W1g + ((size_t)(k0 + k) << 4);
#pragma unroll
            for (int j = 0; j < 16; ++j) acc[j] = fmaf(xk, wr[j], acc[j]);
        }
#pragma unroll
        for (int p = 0; p < 8; ++p) rg[p] = rn[p];
    }

    if (myrow < N_NODES) {
        uint4 o0, o1;
        o0.x = (unsigned)f2bf(acc[0])  | ((unsigned)f2bf(acc[1])  << 16);
        o0.y = (unsigned)f2bf(acc[2])  | ((unsigned)f2bf(acc[3])  << 16);
        o0.z = (unsigned)f2bf(acc[4])  | ((unsigned)f2bf(acc[5])  << 16);
        o0.w = (unsigned)f2bf(acc[6])  | ((unsigned)f2bf(acc[7])  << 16);
        o1.x = (unsigned)f2bf(acc[8])  | ((unsigned)f2bf(acc[9])  << 16);
        o1.y = (unsigned)f2bf(acc[10]) | ((unsigned)f2bf(acc[11]) << 16);
        o1.z = (unsigned)f2bf(acc[12]) | ((unsigned)f2bf(acc[13]) << 16);
        o1.w = (unsigned)f2bf(acc[14]) | ((unsigned)f2bf(acc[15]) << 16);
        uint4* o = (uint4*)(h1b + (size_t)myrow * HIDDEN);
        o[0] = o0; o[1] = o1;
    }
}

// ---------- gather layer 1 (+ bias + self-loop) fused with gemm2 ----------
// 16 lanes/node = 4 es x 4 fs; h1 in bf16 (8B/lane); dinv[r] inline
// (broadcast-coalesced L1 hit); unroll-2 dual accumulators.

__global__ __launch_bounds__(256)
void k_gather1(const int* __restrict__ startA, const uint2* __restrict__ ep,
               const float* __restrict__ dinv, const unsigned short* __restrict__ h1b,
               const float* __restrict__ b1, const float* __restrict__ W2g,
               float* __restrict__ x1, float* __restrict__ h2p) {
    __shared__ float sW2[HIDDEN * NCLS];
    __shared__ float sv[16][HIDDEN + 1];
    int t = threadIdx.x;
    if (t < HIDDEN * NCLS) sW2[t] = W2g[t];
    int ln = t >> 4, es = (t >> 2) & 3, fs = t & 3;
    int i = blockIdx.x * 16 + ln;
    bool act = (i < N_NODES);
    float4 a = make_float4(0.0f, 0.0f, 0.0f, 0.0f);
    float4 b = make_float4(0.0f, 0.0f, 0.0f, 0.0f);
    if (act) {
        int s0 = startA[i], n = startA[i + 1] - s0;
        int k = es;
        for (; k + 4 < n; k += 8) {
            uint2 e0 = ep[s0 + k];
            uint2 e1 = ep[s0 + k + 4];
            int r0 = (int)e0.x, r1 = (int)e1.x;
            float w0 = __uint_as_float(e0.y) * dinv[r0];
            float w1 = __uint_as_float(e1.y) * dinv[r1];
            uint2 p0 = *(const uint2*)(h1b + ((size_t)r0 << 4) + 4 * fs);
            uint2 p1 = *(const uint2*)(h1b + ((size_t)r1 << 4) + 4 * fs);
            a.x = fmaf(w0, __uint_as_float(p0.x << 16),          a.x);
            a.y = fmaf(w0, __uint_as_float(p0.x & 0xFFFF0000u),  a.y);
            a.z = fmaf(w0, __uint_as_float(p0.y << 16),          a.z);
            a.w = fmaf(w0, __uint_as_float(p0.y & 0xFFFF0000u),  a.w);
            b.x = fmaf(w1, __uint_as_float(p1.x << 16),          b.x);
            b.y = fmaf(w1, __uint_as_float(p1.x & 0xFFFF0000u),  b.y);
            b.z = fmaf(w1, __uint_as_float(p1.y << 16),          b.z);
            b.w = fmaf(w1, __uint_as_float(p1.y & 0xFFFF0000u),  b.w);
        }
        if (k < n) {
            uint2 e0 = ep[s0 + k];
            int r0 = (int)e0.x;
            float w0 = __uint_as_float(e0.y) * dinv[r0];
            uint2 p0 = *(const uint2*)(h1b + ((size_t)r0 << 4) + 4 * fs);
            a.x = fmaf(w0, __uint_as_float(p0.x << 16),          a.x);
            a.y = fmaf(w0, __uint_as_float(p0.x & 0xFFFF0000u),  a.y);
            a.z = fmaf(w0, __uint_as_float(p0.y << 16),          a.z);
            a.w = fmaf(w0, __uint_as_float(p0.y & 0xFFFF0000u),  a.w);
        }
    }
    a.x += b.x; a.y += b.y; a.z += b.z; a.w += b.w;
    a.x += __shfl_xor(a.x, 4); a.y += __shfl_xor(a.y, 4);
    a.z += __shfl_xor(a.z, 4); a.w += __shfl_xor(a.w, 4);
    a.x += __shfl_xor(a.x, 8); a.y += __shfl_xor(a.y, 8);
    a.z += __shfl_xor(a.z, 8); a.w += __shfl_xor(a.w, 8);
    if (act && es == 0) {
        float di = dinv[i], d2 = di * di;
        uint2 ps = *(const uint2*)(h1b + ((size_t)i << 4) + 4 * fs);
        const float* b1r = b1 + 4 * fs;
        float v0 = di * a.x + d2 * __uint_as_float(ps.x << 16)         + b1r[0];
        float v1 = di * a.y + d2 * __uint_as_float(ps.x & 0xFFFF0000u) + b1r[1];
        float v2 = di * a.z + d2 * __uint_as_float(ps.y << 16)         + b1r[2];
        float v3 = di * a.w + d2 * __uint_as_float(ps.y & 0xFFFF0000u) + b1r[3];
        *(float4*)(x1 + (size_t)i * HIDDEN + 4 * fs) = make_float4(v0, v1, v2, v3);
        sv[ln][4 * fs + 0] = v0; sv[ln][4 * fs + 1] = v1;
        sv[ln][4 * fs + 2] = v2; sv[ln][4 * fs + 3] = v3;
    }
    __syncthreads();
    int j = t & 15;
    if (act && j < 8) {
        float acc2 = 0.0f;
        if (j < NCLS) {
#pragma unroll
            for (int kk = 0; kk < HIDDEN; ++kk)
                acc2 = fmaf(sv[ln][kk], sW2[kk * NCLS + j], acc2);
        }
        h2p[(size_t)i * 8 + j] = acc2;             // cols 6,7 = 0 pad
    }
}

// ---------- gather layer 2 fused with log_softmax ----------
// 16 lanes/node = 8 es x 2 fs on padded f32 h2p[N,8]; dinv[r] inline.

__global__ __launch_bounds__(256)
void k_gather2(const int* __restrict__ startA, const uint2* __restrict__ ep,
               const float* __restrict__ dinv, const float* __restrict__ h2p,
               const float* __restrict__ b2, float* __restrict__ out) {
    __shared__ float sv[16][9];
    int t = threadIdx.x;
    int ln = t >> 4, es = (t >> 1) & 7, fs = t & 1;
    int i = blockIdx.x * 16 + ln;
    bool act = (i < N_NODES);
    float4 a = make_float4(0.0f, 0.0f, 0.0f, 0.0f);
    float4 b = make_float4(0.0f, 0.0f, 0.0f, 0.0f);
    if (act) {
        int s0 = startA[i], n = startA[i + 1] - s0;
        int k = es;
        for (; k + 8 < n; k += 16) {
            uint2 e0 = ep[s0 + k];
            uint2 e1 = ep[s0 + k + 8];
            int r0 = (int)e0.x, r1 = (int)e1.x;
            float w0 = __uint_as_float(e0.y) * dinv[r0];
            float w1 = __uint_as_float(e1.y) * dinv[r1];
            float4 h0 = *(const float4*)(h2p + ((size_t)r0 << 3) + 4 * fs);
            float4 h8 = *(const float4*)(h2p + ((size_t)r1 << 3) + 4 * fs);
            a.x = fmaf(w0, h0.x, a.x); a.y = fmaf(w0, h0.y, a.y);
            a.z = fmaf(w0, h0.z, a.z); a.w = fmaf(w0, h0.w, a.w);
            b.x = fmaf(w1, h8.x, b.x); b.y = fmaf(w1, h8.y, b.y);
            b.z = fmaf(w1, h8.z, b.z); b.w = fmaf(w1, h8.w, b.w);
        }
        if (k < n) {
            uint2 e0 = ep[s0 + k];
            int r0 = (int)e0.x;
            float w0 = __uint_as_float(e0.y) * dinv[r0];
            float4 h0 = *(const float4*)(h2p + ((size_t)r0 << 3) + 4 * fs);
            a.x = fmaf(w0, h0.x, a.x); a.y = fmaf(w0, h0.y, a.y);
            a.z = fmaf(w0, h0.z, a.z); a.w = fmaf(w0, h0.w, a.w);
        }
    }
    a.x += b.x; a.y += b.y; a.z += b.z; a.w += b.w;
    a.x += __shfl_xor(a.x, 2); a.y += __shfl_xor(a.y, 2);
    a.z += __shfl_xor(a.z, 2); a.w += __shfl_xor(a.w, 2);
    a.x += __shfl_xor(a.x, 4); a.y += __shfl_xor(a.y, 4);
    a.z += __shfl_xor(a.z, 4); a.w += __shfl_xor(a.w, 4);
    a.x += __shfl_xor(a.x, 8); a.y += __shfl_xor(a.y, 8);
    a.z += __shfl_xor(a.z, 8); a.w += __shfl_xor(a.w, 8);
    if (act && es == 0) {
        float di = dinv[i], d2 = di * di;
        const float* hr = h2p + (size_t)i * 8 + 4 * fs;
        int c0 = 4 * fs;
        float v0 = di * a.x + d2 * hr[0] + ((c0 + 0) < NCLS ? b2[c0 + 0] : 0.0f);
        float v1 = di * a.y + d2 * hr[1] + ((c0 + 1) < NCLS ? b2[c0 + 1] : 0.0f);
        float v2 = di * a.z + d2 * hr[2] + ((c0 + 2) < NCLS ? b2[c0 + 2] : 0.0f);
        float v3 = di * a.w + d2 * hr[3] + ((c0 + 3) < NCLS ? b2[c0 + 3] : 0.0f);
        sv[ln][c0 + 0] = v0; sv[ln][c0 + 1] = v1;
        sv[ln][c0 + 2] = v2; sv[ln][c0 + 3] = v3;
    }
    __syncthreads();
    int j = t & 15;
    if (act && j < NCLS) {
        float m = -1e30f;
#pragma unroll
        for (int c = 0; c < NCLS; ++c) m = fmaxf(m, sv[ln][c]);
        float ssum = 0.0f;
#pragma unroll
        for (int c = 0; c < NCLS; ++c) ssum += __expf(sv[ln][c] - m);
        out[(size_t)i * NCLS + j] = sv[ln][j] - m - __logf(ssum);
    }
}

// ---------- tier-3 atomic fallback kernels (small ws) ----------

__global__ void k_initdeg(float* __restrict__ deg) {
    int i = blockIdx.x * 256 + threadIdx.x;
    if (i < N_NODES) deg[i] = 1.0f;
}

__global__ void k_degacc(const int* __restrict__ ei, const float* __restrict__ w,
                         const int* __restrict__ flag, float* __restrict__ deg) {
    int e = blockIdx.x * 256 + threadIdx.x;
    if (e >= N_EDGES) return;
    int c = eidx(ei, flag[0], N_EDGES + e);
    atomicAdd(&deg[c], w[e]);
}

__global__ void k_dinv(float* __restrict__ deg) {
    int i = blockIdx.x * 256 + threadIdx.x;
    if (i < N_NODES) {
        float d = deg[i];
        deg[i] = (d > 0.0f) ? rsqrtf(d) : 0.0f;
    }
}

__global__ __launch_bounds__(256)
void k_gemm1f(const float* __restrict__ x, const float* __restrict__ W1g,
              float* __restrict__ h1) {
    __shared__ float w1s[D_FEAT * HIDDEN];
    for (int p = threadIdx.x; p < D_FEAT * HIDDEN; p += 256) w1s[p] = W1g[p];
    __syncthreads();
    const int total = N_NODES * HIDDEN;
    for (int t = blockIdx.x * 256 + threadIdx.x; t < total; t += gridDim.x * 256) {
        int i = t >> 4, j = t & 15;
        const float4* xr = (const float4*)(x + (size_t)i * D_FEAT);
        float acc = 0.0f;
#pragma unroll 4
        for (int k4 = 0; k4 < D_FEAT / 4; ++k4) {
            float4 xv = xr[k4];
            int kb = (k4 << 6) + j;
            acc = fmaf(xv.x, w1s[kb],      acc);
            acc = fmaf(xv.y, w1s[kb + 16], acc);
            acc = fmaf(xv.z, w1s[kb + 32], acc);
            acc = fmaf(xv.w, w1s[kb + 48], acc);
        }
        h1[t] = acc;
    }
}

__global__ __launch_bounds__(256)
void k_scatter1(const int* __restrict__ ei, const float* __restrict__ w,
                const int* __restrict__ flag, const float* __restrict__ dinv,
                const float* __restrict__ h1, float* __restrict__ agg1) {
    int t = blockIdx.x * 256 + threadIdx.x;
    if (t >= N_EDGES * HIDDEN) return;
    int e = t >> 4, j = t & 15;
    int is64 = flag[0];
    int r = eidx(ei, is64, e);
    int c = eidx(ei, is64, N_EDGES + e);
    float nrm = dinv[r] * w[e] * dinv[c];
    atomicAdd(&agg1[(size_t)c * HIDDEN + j], nrm * h1[(size_t)r * HIDDEN + j]);
}

__global__ void k_fin1_gemm2(const float* __restrict__ b1, const float* __restrict__ W2,
                             const float* __restrict__ dinv, const float* __restrict__ h1,
                             float* __restrict__ x1, float* __restrict__ h2) {
    int i = blockIdx.x * 256 + threadIdx.x;
    if (i >= N_NODES) return;
    float d2 = dinv[i] * dinv[i];
    float v[HIDDEN];
#pragma unroll
    for (int k = 0; k < HIDDEN; ++k)
        v[k] = x1[(size_t)i * HIDDEN + k] + d2 * h1[(size_t)i * HIDDEN + k] + b1[k];
#pragma unroll
    for (int k = 0; k < HIDDEN; ++k)
        x1[(size_t)i * HIDDEN + k] = v[k];
#pragma unroll
    for (int j = 0; j < NCLS; ++j) {
        float a = 0.0f;
#pragma unroll
        for (int k = 0; k < HIDDEN; ++k) a = fmaf(v[k], W2[k * NCLS + j], a);
        h2[(size_t)i * NCLS + j] = a;
    }
}

__global__ __launch_bounds__(256)
void k_scatter2(const int* __restrict__ ei, const float* __restrict__ w,
                const int* __restrict__ flag, const float* __restrict__ dinv,
                const float* __restrict__ h2, float* __restrict__ agg2) {
    int t = blockIdx.x * 256 + threadIdx.x;
    if (t >= N_EDGES * NCLS) return;
    int e = t / NCLS, j = t - e * NCLS;
    int is64 = flag[0];
    int r = eidx(ei, is64, e);
    int c = eidx(ei, is64, N_EDGES + e);
    float nrm = dinv[r] * w[e] * dinv[c];
    atomicAdd(&agg2[(size_t)c * NCLS + j], nrm * h2[(size_t)r * NCLS + j]);
}

__global__ void k_final(const float* __restrict__ agg2, const float* __restrict__ h2,
                        const float* __restrict__ dinv, const float* __restrict__ b2,
                        float* __restrict__ out) {
    int i = blockIdx.x * 256 + threadIdx.x;
    if (i >= N_NODES) return;
    float d2 = dinv[i] * dinv[i];
    float v[NCLS];
    float m = -1e30f;
#pragma unroll
    for (int j = 0; j < NCLS; ++j) {
        v[j] = agg2[(size_t)i * NCLS + j] + d2 * h2[(size_t)i * NCLS + j] + b2[j];
        m = fmaxf(m, v[j]);
    }
    float s = 0.0f;
#pragma unroll
    for (int j = 0; j < NCLS; ++j) s += __expf(v[j] - m);
    float l = __logf(s);
#pragma unroll
    for (int j = 0; j < NCLS; ++j) out[(size_t)i * NCLS + j] = v[j] - m - l;
}

// ---------- launch ----------

extern "C" void kernel_launch(void* const* d_in, const int* in_sizes, int n_in,
                              void* d_out, int out_size, void* d_ws, size_t ws_size,
                              hipStream_t stream) {
    const float* x  = (const float*)d_in[0];
    const float* W1 = (const float*)d_in[1];
    const float* b1 = (const float*)d_in[2];
    const float* W2 = (const float*)d_in[3];
    const float* b2 = (const float*)d_in[4];
    const float* ew = (const float*)d_in[5];
    const int*   ei = (const int*)d_in[6];

    float* out = (float*)d_out;
    float* lsm = out;                               // [N, 6]
    float* x1  = out + (size_t)N_NODES * NCLS;      // [N, 16]

    const int NB_N = (N_NODES + 255) / 256;         // 391
    const int NB_E = (N_EDGES + 255) / 256;

    float* W    = (float*)d_ws;
    int*   flag = (int*)d_ws;

    // ---- tier-1 layout (4B words) ----
    int*   bcnt    = (int*)(W + 256);        // 783
    int*   bstart  = (int*)(W + 1152);       // 783
    int*   bcursor = (int*)(W + 2048);       // 782
    int*   startA  = (int*)(W + 2944);       // 100001 -> ends 102945
    float* dinvB   = W + 102948;             // 100000 -> ends 202948
    uint2* abuf    = (uint2*)(W + 202948);   // 3.2M uint2 -> ends 6602948; aliased:
    unsigned short* h1b = (unsigned short*)(W + 202948);  // 1.6M bf16 = 800K words
    float* h2p     = W + 1802948;            //   800K padded f32 [N,8]
    uint2* eperm   = (uint2*)(W + 6602948);  // 3.2M uint2 -> ends 13002948
    const size_t NEED = (size_t)13002948 * 4;       // ~52.0 MB

    if (ws_size >= NEED) {
        hipMemsetAsync(bcnt, 0, (NBUK + 1) * 4, stream);
        k_detect<<<1, 64, 0, stream>>>(ei, flag);
        k_bhist <<<NBLK_A, 256, 0, stream>>>(ei, flag, bcnt);
        k_bscan <<<1, 1024, 0, stream>>>(bcnt, bstart, bcursor);
        k_bscat <<<NBLK_A, 256, 0, stream>>>(ei, ew, flag, bcursor, abuf);
        k_bsort <<<NBUK, 256, 0, stream>>>(bstart, abuf, eperm, startA, dinvB);
        k_gemm1 <<<(N_NODES + 127) / 128, 128, 0, stream>>>(x, W1, h1b);
        k_gather1<<<(N_NODES + 15) / 16, 256, 0, stream>>>(startA, eperm, dinvB, h1b,
                                                           b1, W2, x1, h2p);
        k_gather2<<<(N_NODES + 15) / 16, 256, 0, stream>>>(startA, eperm, dinvB, h2p,
                                                           b2, lsm);
    } else {
        float* deg  = W + 1024;
        float* fh1  = W + 101376;
        float* fh2  = fh1 + (size_t)N_NODES * HIDDEN;
        float* agg2 = fh2 + (size_t)N_NODES * NCLS;
        hipMemsetAsync(x1,   0, (size_t)N_NODES * HIDDEN * sizeof(float), stream);
        hipMemsetAsync(agg2, 0, (size_t)N_NODES * NCLS   * sizeof(float), stream);
        k_detect <<<1, 64, 0, stream>>>(ei, flag);
        k_initdeg<<<NB_N, 256, 0, stream>>>(deg);
        k_degacc <<<NB_E, 256, 0, stream>>>(ei, ew, flag, deg);
        k_dinv   <<<NB_N, 256, 0, stream>>>(deg);
        k_gemm1f <<<2048, 256, 0, stream>>>(x, W1, fh1);
        k_scatter1<<<(N_EDGES * HIDDEN + 255) / 256, 256, 0, stream>>>(ei, ew, flag, deg, fh1, x1);
        k_fin1_gemm2<<<NB_N, 256, 0, stream>>>(b1, W2, deg, fh1, x1, fh2);
        k_scatter2<<<(N_EDGES * NCLS + 255) / 256, 256, 0, stream>>>(ei, ew, flag, deg, fh2, agg2);
        k_final  <<<NB_N, 256, 0, stream>>>(agg2, fh2, deg, b2, lsm);
    }
}

// Round 10
// 324.633 us; speedup vs baseline: 1.0001x; 1.0001x over previous
//
#include <hip/hip_runtime.h>

#define N_NODES 100000
#define N_EDGES 3200000
#define D_FEAT  512
#define HIDDEN  16
#define NCLS    6
#define BSH     7                      // bucket = col >> 7
#define BNODES  128                    // nodes per bucket
#define NBUK    782                    // ceil(N_NODES/128)
#define BCAP    6144                   // LDS bucket capacity (avg 4092, +32 sigma)
#define NBLK_A  512                    // build blocks: exactly 2 per CU
#define TILE    6250                   // ceil(N_EDGES/NBLK_A)

// ---------- helpers ----------

__device__ __forceinline__ int eidx(const int* __restrict__ ei, int is64, int pos) {
    return is64 ? ei[2 * (long long)pos] : ei[pos];
}

__global__ void k_detect(const int* __restrict__ ei, int* __restrict__ flag) {
    int v = ei[2 * threadIdx.x + 1];
    unsigned long long b = __ballot(v != 0);
    if (threadIdx.x == 0) flag[0] = (b == 0ULL) ? 1 : 0;
}

__device__ __forceinline__ unsigned short f2bf(float f) {     // RNE f32->bf16
    unsigned u = __float_as_uint(f);
    return (unsigned short)((u + 0x7FFFu + ((u >> 16) & 1u)) >> 16);
}

// ---------- bucket build ----------

__global__ __launch_bounds__(256)
void k_bhist(const int* __restrict__ ei, const int* __restrict__ flag,
             int* __restrict__ bcnt) {
    __shared__ int lh[NBUK];
    for (int i = threadIdx.x; i < NBUK; i += 256) lh[i] = 0;
    __syncthreads();
    int is64 = flag[0];
    int s = blockIdx.x * TILE, e1 = min(s + TILE, N_EDGES);
    for (int e = s + threadIdx.x; e < e1; e += 256) {
        int c = eidx(ei, is64, N_EDGES + e);
        atomicAdd(&lh[c >> BSH], 1);
    }
    __syncthreads();
    for (int i = threadIdx.x; i < NBUK; i += 256)
        if (lh[i]) atomicAdd(&bcnt[i], lh[i]);
}

__global__ void k_bscan(const int* __restrict__ bcnt, int* __restrict__ bstart,
                        int* __restrict__ bcursor) {
    __shared__ int s[1024];
    int t = threadIdx.x;
    int v = (t < NBUK) ? bcnt[t] : 0;
    s[t] = v;
    __syncthreads();
    for (int off = 1; off < 1024; off <<= 1) {
        int u = (t >= off) ? s[t - off] : 0;
        __syncthreads();
        s[t] += u;
        __syncthreads();
    }
    int excl = s[t] - v;
    if (t <= NBUK) bstart[t] = excl;
    if (t < NBUK)  bcursor[t] = excl;
}

// scatter edges into bucket-major abuf with block-reserved runs
// pack: x = row | (col&127)<<17  (row < 2^17), y = bits(w)
__global__ __launch_bounds__(256)
void k_bscat(const int* __restrict__ ei, const float* __restrict__ ew,
             const int* __restrict__ flag, int* __restrict__ bcursor,
             uint2* __restrict__ abuf) {
    __shared__ int lh[NBUK];
    __shared__ int lbase[NBUK];
    __shared__ int lcur[NBUK];
    for (int i = threadIdx.x; i < NBUK; i += 256) { lh[i] = 0; lcur[i] = 0; }
    __syncthreads();
    int is64 = flag[0];
    int s = blockIdx.x * TILE, e1 = min(s + TILE, N_EDGES);
    for (int e = s + threadIdx.x; e < e1; e += 256) {
        int c = eidx(ei, is64, N_EDGES + e);
        atomicAdd(&lh[c >> BSH], 1);
    }
    __syncthreads();
    for (int i = threadIdx.x; i < NBUK; i += 256)
        if (lh[i]) lbase[i] = atomicAdd(&bcursor[i], lh[i]);
    __syncthreads();
    for (int e = s + threadIdx.x; e < e1; e += 256) {
        int r = eidx(ei, is64, e);
        int c = eidx(ei, is64, N_EDGES + e);
        float w = ew[e];
        int b = c >> BSH;
        int off = atomicAdd(&lcur[b], 1);
        abuf[lbase[b] + off] = make_uint2((unsigned)r | ((unsigned)(c & (BNODES - 1)) << 17),
                                          __float_as_uint(w));
    }
}

// per-bucket counting sort (LDS-staged): abuf -> eperm {row, raw w};
// emits startA and dinv (cnt+wsum fused, single abuf read).
__global__ __launch_bounds__(256)
void k_bsort(const int* __restrict__ bstart, const uint2* __restrict__ abuf,
             uint2* __restrict__ eperm, int* __restrict__ startA,
             float* __restrict__ dinv) {
    __shared__ uint2 se[BCAP];                     // 48 KB
    __shared__ int   cnt[BNODES];
    __shared__ int   scn[256];
    __shared__ int   cur[BNODES];
    __shared__ float wsum[BNODES];
    int t = threadIdx.x, b = blockIdx.x;
    int s0 = bstart[b], s1 = bstart[b + 1];
    int nb = s1 - s0;
    if (t < BNODES) { cnt[t] = 0; wsum[t] = 0.0f; }
    __syncthreads();

    bool fits = (nb <= BCAP);
    if (fits) {
        for (int k = t; k < nb; k += 256) {
            uint2 a = abuf[s0 + k];
            se[k] = a;
            int ln = (int)(a.x >> 17);
            atomicAdd(&cnt[ln], 1);
            atomicAdd(&wsum[ln], __uint_as_float(a.y));
        }
    } else {
        for (int k = t; k < nb; k += 256) {
            uint2 a = abuf[s0 + k];
            int ln = (int)(a.x >> 17);
            atomicAdd(&cnt[ln], 1);
            atomicAdd(&wsum[ln], __uint_as_float(a.y));
        }
    }
    __syncthreads();
    int v = (t < BNODES) ? cnt[t] : 0;
    scn[t] = v;
    __syncthreads();
    for (int off = 1; off < 256; off <<= 1) {
        int u = (t >= off) ? scn[t - off] : 0;
        __syncthreads();
        scn[t] += u;
        __syncthreads();
    }
    int excl = scn[t] - v;
    if (t < BNODES) {
        cur[t] = excl;
        int node = b * BNODES + t;
        if (node <= N_NODES) startA[node] = s0 + excl;
        if (node <  N_NODES) dinv[node] = rsqrtf(1.0f + wsum[t]);
    }
    __syncthreads();
    if (fits) {
        for (int k = t; k < nb; k += 256) {
            uint2 a = se[k];
            int ln = (int)(a.x >> 17);
            int off = atomicAdd(&cur[ln], 1);
            eperm[s0 + off] = make_uint2(a.x & 0x1FFFFu, a.y);
        }
    } else {
        for (int k = t; k < nb; k += 256) {
            uint2 a = abuf[s0 + k];
            int ln = (int)(a.x >> 17);
            int off = atomicAdd(&cur[ln], 1);
            eperm[s0 + off] = make_uint2(a.x & 0x1FFFFu, a.y);
        }
    }
}

// ---------- layer 1 transform: h1 = x @ W1 (bf16 output, 32B rows) ----------
// 128 rows/block x 782 blocks. x tile transposed in LDS (pad 129).
// __launch_bounds__(128, 1): VGPR cap 256 so the 8-deep register double-buffer
// (rg[8]+rn[8]=64 VGPR) stays in flight -- at the default cap (56 VGPR, R9
// profile) the compiler serialized the prefetch into ~8 sequential latencies
// per chunk => 150us. With pipelined loads the chunk latency hides under the
// 512-FMA compute phase.

__global__ __launch_bounds__(128, 1)
void k_gemm1(const float* __restrict__ x, const float* __restrict__ W1g,
             unsigned short* __restrict__ h1b) {
    __shared__ float xT[32 * 129];          // 16.5 KB
    const int t = threadIdx.x;
    const int row0 = blockIdx.x * 128;
    const int myrow = row0 + t;

    float4 rg[8], rn[8];
#pragma unroll
    for (int p = 0; p < 8; ++p) {
        int f = t + 128 * p;
        int lr = f >> 3, lc = f & 7;
        int gr = min(row0 + lr, N_NODES - 1);
        rg[p] = *(const float4*)(x + (size_t)gr * D_FEAT + 4 * lc);
    }

    float acc[16];
#pragma unroll
    for (int j = 0; j < 16; ++j) acc[j] = 0.0f;

    for (int ch = 0; ch < 16; ++ch) {
        __syncthreads();
#pragma unroll
        for (int p = 0; p < 8; ++p) {
            int f = t + 128 * p;
            int lr = f >> 3, lc = f & 7;
            xT[(4 * lc + 0) * 129 + lr] = rg[p].x;
            xT[(4 * lc + 1) * 129 + lr] = rg[p].y;
            xT[(4 * lc + 2) * 129 + lr] = rg[p].z;
            xT[(4 * lc + 3) * 129 + lr] = rg[p].w;
        }
        if (ch < 15) {
            int k0n = (ch + 1) * 32;
#pragma unroll
            for (int p = 0; p < 8; ++p) {
                int f = t + 128 * p;
                int lr = f >> 3, lc = f & 7;
                int gr = min(row0 + lr, N_NODES - 1);
                rn[p] = *(const float4*)(x + (size_t)gr * D_FEAT + k0n + 4 * lc);
            }
        }
        __syncthreads();
        const int k0 = ch * 32;
#pragma unroll
        for (int k = 0; k < 32; ++k) {
            float xk = xT[k * 129 + t];
            const float* wr = W1g + ((size_t)(k0 + k) << 4);
#pragma unroll
            for (int j = 0; j < 16; ++j) acc[j] = fmaf(xk, wr[j], acc[j]);
        }
#pragma unroll
        for (int p = 0; p < 8; ++p) rg[p] = rn[p];
    }

    if (myrow < N_NODES) {
        uint4 o0, o1;
        o0.x = (unsigned)f2bf(acc[0])  | ((unsigned)f2bf(acc[1])  << 16);
        o0.y = (unsigned)f2bf(acc[2])  | ((unsigned)f2bf(acc[3])  << 16);
        o0.z = (unsigned)f2bf(acc[4])  | ((unsigned)f2bf(acc[5])  << 16);
        o0.w = (unsigned)f2bf(acc[6])  | ((unsigned)f2bf(acc[7])  << 16);
        o1.x = (unsigned)f2bf(acc[8])  | ((unsigned)f2bf(acc[9])  << 16);
        o1.y = (unsigned)f2bf(acc[10]) | ((unsigned)f2bf(acc[11]) << 16);
        o1.z = (unsigned)f2bf(acc[12]) | ((unsigned)f2bf(acc[13]) << 16);
        o1.w = (unsigned)f2bf(acc[14]) | ((unsigned)f2bf(acc[15]) << 16);
        uint4* o = (uint4*)(h1b + (size_t)myrow * HIDDEN);
        o[0] = o0; o[1] = o1;
    }
}

// ---------- gather layer 1 (+ bias + self-loop) fused with gemm2 ----------
// 16 lanes/node = 4 es x 4 fs; h1 in bf16 (8B/lane); dinv[r] inline;
// unroll-2 dual accumulators.

__global__ __launch_bounds__(256)
void k_gather1(const int* __restrict__ startA, const uint2* __restrict__ ep,
               const float* __restrict__ dinv, const unsigned short* __restrict__ h1b,
               const float* __restrict__ b1, const float* __restrict__ W2g,
               float* __restrict__ x1, float* __restrict__ h2p) {
    __shared__ float sW2[HIDDEN * NCLS];
    __shared__ float sv[16][HIDDEN + 1];
    int t = threadIdx.x;
    if (t < HIDDEN * NCLS) sW2[t] = W2g[t];
    int ln = t >> 4, es = (t >> 2) & 3, fs = t & 3;
    int i = blockIdx.x * 16 + ln;
    bool act = (i < N_NODES);
    float4 a = make_float4(0.0f, 0.0f, 0.0f, 0.0f);
    float4 b = make_float4(0.0f, 0.0f, 0.0f, 0.0f);
    if (act) {
        int s0 = startA[i], n = startA[i + 1] - s0;
        int k = es;
        for (; k + 4 < n; k += 8) {
            uint2 e0 = ep[s0 + k];
            uint2 e1 = ep[s0 + k + 4];
            int r0 = (int)e0.x, r1 = (int)e1.x;
            float w0 = __uint_as_float(e0.y) * dinv[r0];
            float w1 = __uint_as_float(e1.y) * dinv[r1];
            uint2 p0 = *(const uint2*)(h1b + ((size_t)r0 << 4) + 4 * fs);
            uint2 p1 = *(const uint2*)(h1b + ((size_t)r1 << 4) + 4 * fs);
            a.x = fmaf(w0, __uint_as_float(p0.x << 16),          a.x);
            a.y = fmaf(w0, __uint_as_float(p0.x & 0xFFFF0000u),  a.y);
            a.z = fmaf(w0, __uint_as_float(p0.y << 16),          a.z);
            a.w = fmaf(w0, __uint_as_float(p0.y & 0xFFFF0000u),  a.w);
            b.x = fmaf(w1, __uint_as_float(p1.x << 16),          b.x);
            b.y = fmaf(w1, __uint_as_float(p1.x & 0xFFFF0000u),  b.y);
            b.z = fmaf(w1, __uint_as_float(p1.y << 16),          b.z);
            b.w = fmaf(w1, __uint_as_float(p1.y & 0xFFFF0000u),  b.w);
        }
        if (k < n) {
            uint2 e0 = ep[s0 + k];
            int r0 = (int)e0.x;
            float w0 = __uint_as_float(e0.y) * dinv[r0];
            uint2 p0 = *(const uint2*)(h1b + ((size_t)r0 << 4) + 4 * fs);
            a.x = fmaf(w0, __uint_as_float(p0.x << 16),          a.x);
            a.y = fmaf(w0, __uint_as_float(p0.x & 0xFFFF0000u),  a.y);
            a.z = fmaf(w0, __uint_as_float(p0.y << 16),          a.z);
            a.w = fmaf(w0, __uint_as_float(p0.y & 0xFFFF0000u),  a.w);
        }
    }
    a.x += b.x; a.y += b.y; a.z += b.z; a.w += b.w;
    a.x += __shfl_xor(a.x, 4); a.y += __shfl_xor(a.y, 4);
    a.z += __shfl_xor(a.z, 4); a.w += __shfl_xor(a.w, 4);
    a.x += __shfl_xor(a.x, 8); a.y += __shfl_xor(a.y, 8);
    a.z += __shfl_xor(a.z, 8); a.w += __shfl_xor(a.w, 8);
    if (act && es == 0) {
        float di = dinv[i], d2 = di * di;
        uint2 ps = *(const uint2*)(h1b + ((size_t)i << 4) + 4 * fs);
        const float* b1r = b1 + 4 * fs;
        float v0 = di * a.x + d2 * __uint_as_float(ps.x << 16)         + b1r[0];
        float v1 = di * a.y + d2 * __uint_as_float(ps.x & 0xFFFF0000u) + b1r[1];
        float v2 = di * a.z + d2 * __uint_as_float(ps.y << 16)         + b1r[2];
        float v3 = di * a.w + d2 * __uint_as_float(ps.y & 0xFFFF0000u) + b1r[3];
        *(float4*)(x1 + (size_t)i * HIDDEN + 4 * fs) = make_float4(v0, v1, v2, v3);
        sv[ln][4 * fs + 0] = v0; sv[ln][4 * fs + 1] = v1;
        sv[ln][4 * fs + 2] = v2; sv[ln][4 * fs + 3] = v3;
    }
    __syncthreads();
    int j = t & 15;
    if (act && j < 8) {
        float acc2 = 0.0f;
        if (j < NCLS) {
#pragma unroll
            for (int kk = 0; kk < HIDDEN; ++kk)
                acc2 = fmaf(sv[ln][kk], sW2[kk * NCLS + j], acc2);
        }
        h2p[(size_t)i * 8 + j] = acc2;             // cols 6,7 = 0 pad
    }
}

// ---------- gather layer 2 fused with log_softmax ----------
// 16 lanes/node = 8 es x 2 fs on padded f32 h2p[N,8]; dinv[r] inline.

__global__ __launch_bounds__(256)
void k_gather2(const int* __restrict__ startA, const uint2* __restrict__ ep,
               const float* __restrict__ dinv, const float* __restrict__ h2p,
               const float* __restrict__ b2, float* __restrict__ out) {
    __shared__ float sv[16][9];
    int t = threadIdx.x;
    int ln = t >> 4, es = (t >> 1) & 7, fs = t & 1;
    int i = blockIdx.x * 16 + ln;
    bool act = (i < N_NODES);
    float4 a = make_float4(0.0f, 0.0f, 0.0f, 0.0f);
    float4 b = make_float4(0.0f, 0.0f, 0.0f, 0.0f);
    if (act) {
        int s0 = startA[i], n = startA[i + 1] - s0;
        int k = es;
        for (; k + 8 < n; k += 16) {
            uint2 e0 = ep[s0 + k];
            uint2 e1 = ep[s0 + k + 8];
            int r0 = (int)e0.x, r1 = (int)e1.x;
            float w0 = __uint_as_float(e0.y) * dinv[r0];
            float w1 = __uint_as_float(e1.y) * dinv[r1];
            float4 h0 = *(const float4*)(h2p + ((size_t)r0 << 3) + 4 * fs);
            float4 h8 = *(const float4*)(h2p + ((size_t)r1 << 3) + 4 * fs);
            a.x = fmaf(w0, h0.x, a.x); a.y = fmaf(w0, h0.y, a.y);
            a.z = fmaf(w0, h0.z, a.z); a.w = fmaf(w0, h0.w, a.w);
            b.x = fmaf(w1, h8.x, b.x); b.y = fmaf(w1, h8.y, b.y);
            b.z = fmaf(w1, h8.z, b.z); b.w = fmaf(w1, h8.w, b.w);
        }
        if (k < n) {
            uint2 e0 = ep[s0 + k];
            int r0 = (int)e0.x;
            float w0 = __uint_as_float(e0.y) * dinv[r0];
            float4 h0 = *(const float4*)(h2p + ((size_t)r0 << 3) + 4 * fs);
            a.x = fmaf(w0, h0.x, a.x); a.y = fmaf(w0, h0.y, a.y);
            a.z = fmaf(w0, h0.z, a.z); a.w = fmaf(w0, h0.w, a.w);
        }
    }
    a.x += b.x; a.y += b.y; a.z += b.z; a.w += b.w;
    a.x += __shfl_xor(a.x, 2); a.y += __shfl_xor(a.y, 2);
    a.z += __shfl_xor(a.z, 2); a.w += __shfl_xor(a.w, 2);
    a.x += __shfl_xor(a.x, 4); a.y += __shfl_xor(a.y, 4);
    a.z += __shfl_xor(a.z, 4); a.w += __shfl_xor(a.w, 4);
    a.x += __shfl_xor(a.x, 8); a.y += __shfl_xor(a.y, 8);
    a.z += __shfl_xor(a.z, 8); a.w += __shfl_xor(a.w, 8);
    if (act && es == 0) {
        float di = dinv[i], d2 = di * di;
        const float* hr = h2p + (size_t)i * 8 + 4 * fs;
        int c0 = 4 * fs;
        float v0 = di * a.x + d2 * hr[0] + ((c0 + 0) < NCLS ? b2[c0 + 0] : 0.0f);
        float v1 = di * a.y + d2 * hr[1] + ((c0 + 1) < NCLS ? b2[c0 + 1] : 0.0f);
        float v2 = di * a.z + d2 * hr[2] + ((c0 + 2) < NCLS ? b2[c0 + 2] : 0.0f);
        float v3 = di * a.w + d2 * hr[3] + ((c0 + 3) < NCLS ? b2[c0 + 3] : 0.0f);
        sv[ln][c0 + 0] = v0; sv[ln][c0 + 1] = v1;
        sv[ln][c0 + 2] = v2; sv[ln][c0 + 3] = v3;
    }
    __syncthreads();
    int j = t & 15;
    if (act && j < NCLS) {
        float m = -1e30f;
#pragma unroll
        for (int c = 0; c < NCLS; ++c) m = fmaxf(m, sv[ln][c]);
        float ssum = 0.0f;
#pragma unroll
        for (int c = 0; c < NCLS; ++c) ssum += __expf(sv[ln][c] - m);
        out[(size_t)i * NCLS + j] = sv[ln][j] - m - __logf(ssum);
    }
}

// ---------- tier-3 atomic fallback kernels (small ws) ----------

__global__ void k_initdeg(float* __restrict__ deg) {
    int i = blockIdx.x * 256 + threadIdx.x;
    if (i < N_NODES) deg[i] = 1.0f;
}

__global__ void k_degacc(const int* __restrict__ ei, const float* __restrict__ w,
                         const int* __restrict__ flag, float* __restrict__ deg) {
    int e = blockIdx.x * 256 + threadIdx.x;
    if (e >= N_EDGES) return;
    int c = eidx(ei, flag[0], N_EDGES + e);
    atomicAdd(&deg[c], w[e]);
}

__global__ void k_dinv(float* __restrict__ deg) {
    int i = blockIdx.x * 256 + threadIdx.x;
    if (i < N_NODES) {
        float d = deg[i];
        deg[i] = (d > 0.0f) ? rsqrtf(d) : 0.0f;
    }
}

__global__ __launch_bounds__(256)
void k_gemm1f(const float* __restrict__ x, const float* __restrict__ W1g,
              float* __restrict__ h1) {
    __shared__ float w1s[D_FEAT * HIDDEN];
    for (int p = threadIdx.x; p < D_FEAT * HIDDEN; p += 256) w1s[p] = W1g[p];
    __syncthreads();
    const int total = N_NODES * HIDDEN;
    for (int t = blockIdx.x * 256 + threadIdx.x; t < total; t += gridDim.x * 256) {
        int i = t >> 4, j = t & 15;
        const float4* xr = (const float4*)(x + (size_t)i * D_FEAT);
        float acc = 0.0f;
#pragma unroll 4
        for (int k4 = 0; k4 < D_FEAT / 4; ++k4) {
            float4 xv = xr[k4];
            int kb = (k4 << 6) + j;
            acc = fmaf(xv.x, w1s[kb],      acc);
            acc = fmaf(xv.y, w1s[kb + 16], acc);
            acc = fmaf(xv.z, w1s[kb + 32], acc);
            acc = fmaf(xv.w, w1s[kb + 48], acc);
        }
        h1[t] = acc;
    }
}

__global__ __launch_bounds__(256)
void k_scatter1(const int* __restrict__ ei, const float* __restrict__ w,
                const int* __restrict__ flag, const float* __restrict__ dinv,
                const float* __restrict__ h1, float* __restrict__ agg1) {
    int t = blockIdx.x * 256 + threadIdx.x;
    if (t >= N_EDGES * HIDDEN) return;
    int e = t >> 4, j = t & 15;
    int is64 = flag[0];
    int r = eidx(ei, is64, e);
    int c = eidx(ei, is64, N_EDGES + e);
    float nrm = dinv[r] * w[e] * dinv[c];
    atomicAdd(&agg1[(size_t)c * HIDDEN + j], nrm * h1[(size_t)r * HIDDEN + j]);
}

__global__ void k_fin1_gemm2(const float* __restrict__ b1, const float* __restrict__ W2,
                             const float* __restrict__ dinv, const float* __restrict__ h1,
                             float* __restrict__ x1, float* __restrict__ h2) {
    int i = blockIdx.x * 256 + threadIdx.x;
    if (i >= N_NODES) return;
    float d2 = dinv[i] * dinv[i];
    float v[HIDDEN];
#pragma unroll
    for (int k = 0; k < HIDDEN; ++k)
        v[k] = x1[(size_t)i * HIDDEN + k] + d2 * h1[(size_t)i * HIDDEN + k] + b1[k];
#pragma unroll
    for (int k = 0; k < HIDDEN; ++k)
        x1[(size_t)i * HIDDEN + k] = v[k];
#pragma unroll
    for (int j = 0; j < NCLS; ++j) {
        float a = 0.0f;
#pragma unroll
        for (int k = 0; k < HIDDEN; ++k) a = fmaf(v[k], W2[k * NCLS + j], a);
        h2[(size_t)i * NCLS + j] = a;
    }
}

__global__ __launch_bounds__(256)
void k_scatter2(const int* __restrict__ ei, const float* __restrict__ w,
                const int* __restrict__ flag, const float* __restrict__ dinv,
                const float* __restrict__ h2, float* __restrict__ agg2) {
    int t = blockIdx.x * 256 + threadIdx.x;
    if (t >= N_EDGES * NCLS) return;
    int e = t / NCLS, j = t - e * NCLS;
    int is64 = flag[0];
    int r = eidx(ei, is64, e);
    int c = eidx(ei, is64, N_EDGES + e);
    float nrm = dinv[r] * w[e] * dinv[c];
    atomicAdd(&agg2[(size_t)c * NCLS + j], nrm * h2[(size_t)r * NCLS + j]);
}

__global__ void k_final(const float* __restrict__ agg2, const float* __restrict__ h2,
                        const float* __restrict__ dinv, const float* __restrict__ b2,
                        float* __restrict__ out) {
    int i = blockIdx.x * 256 + threadIdx.x;
    if (i >= N_NODES) return;
    float d2 = dinv[i] * dinv[i];
    float v[NCLS];
    float m = -1e30f;
#pragma unroll
    for (int j = 0; j < NCLS; ++j) {
        v[j] = agg2[(size_t)i * NCLS + j] + d2 * h2[(size_t)i * NCLS + j] + b2[j];
        m = fmaxf(m, v[j]);
    }
    float s = 0.0f;
#pragma unroll
    for (int j = 0; j < NCLS; ++j) s += __expf(v[j] - m);
    float l = __logf(s);
#pragma unroll
    for (int j = 0; j < NCLS; ++j) out[(size_t)i * NCLS + j] = v[j] - m - l;
}

// ---------- launch ----------

extern "C" void kernel_launch(void* const* d_in, const int* in_sizes, int n_in,
                              void* d_out, int out_size, void* d_ws, size_t ws_size,
                              hipStream_t stream) {
    const float* x  = (const float*)d_in[0];
    const float* W1 = (const float*)d_in[1];
    const float* b1 = (const float*)d_in[2];
    const float* W2 = (const float*)d_in[3];
    const float* b2 = (const float*)d_in[4];
    const float* ew = (const float*)d_in[5];
    const int*   ei = (const int*)d_in[6];

    float* out = (float*)d_out;
    float* lsm = out;                               // [N, 6]
    float* x1  = out + (size_t)N_NODES * NCLS;      // [N, 16]

    const int NB_N = (N_NODES + 255) / 256;         // 391
    const int NB_E = (N_EDGES + 255) / 256;

    float* W    = (float*)d_ws;
    int*   flag = (int*)d_ws;

    // ---- tier-1 layout (4B words) ----
    int*   bcnt    = (int*)(W + 256);        // 783
    int*   bstart  = (int*)(W + 1152);       // 783
    int*   bcursor = (int*)(W + 2048);       // 782
    int*   startA  = (int*)(W + 2944);       // 100001 -> ends 102945
    float* dinvB   = W + 102948;             // 100000 -> ends 202948
    uint2* abuf    = (uint2*)(W + 202948);   // 3.2M uint2 -> ends 6602948; aliased:
    unsigned short* h1b = (unsigned short*)(W + 202948);  // 1.6M bf16 = 800K words
    float* h2p     = W + 1802948;            //   800K padded f32 [N,8]
    uint2* eperm   = (uint2*)(W + 6602948);  // 3.2M uint2 -> ends 13002948
    const size_t NEED = (size_t)13002948 * 4;       // ~52.0 MB

    if (ws_size >= NEED) {
        hipMemsetAsync(bcnt, 0, (NBUK + 1) * 4, stream);
        k_detect<<<1, 64, 0, stream>>>(ei, flag);
        k_bhist <<<NBLK_A, 256, 0, stream>>>(ei, flag, bcnt);
        k_bscan <<<1, 1024, 0, stream>>>(bcnt, bstart, bcursor);
        k_bscat <<<NBLK_A, 256, 0, stream>>>(ei, ew, flag, bcursor, abuf);
        k_bsort <<<NBUK, 256, 0, stream>>>(bstart, abuf, eperm, startA, dinvB);
        k_gemm1 <<<(N_NODES + 127) / 128, 128, 0, stream>>>(x, W1, h1b);
        k_gather1<<<(N_NODES + 15) / 16, 256, 0, stream>>>(startA, eperm, dinvB, h1b,
                                                           b1, W2, x1, h2p);
        k_gather2<<<(N_NODES + 15) / 16, 256, 0, stream>>>(startA, eperm, dinvB, h2p,
                                                           b2, lsm);
    } else {
        float* deg  = W + 1024;
        float* fh1  = W + 101376;
        float* fh2  = fh1 + (size_t)N_NODES * HIDDEN;
        float* agg2 = fh2 + (size_t)N_NODES * NCLS;
        hipMemsetAsync(x1,   0, (size_t)N_NODES * HIDDEN * sizeof(float), stream);
        hipMemsetAsync(agg2, 0, (size_t)N_NODES * NCLS   * sizeof(float), stream);
        k_detect <<<1, 64, 0, stream>>>(ei, flag);
        k_initdeg<<<NB_N, 256, 0, stream>>>(deg);
        k_degacc <<<NB_E, 256, 0, stream>>>(ei, ew, flag, deg);
        k_dinv   <<<NB_N, 256, 0, stream>>>(deg);
        k_gemm1f <<<2048, 256, 0, stream>>>(x, W1, fh1);
        k_scatter1<<<(N_EDGES * HIDDEN + 255) / 256, 256, 0, stream>>>(ei, ew, flag, deg, fh1, x1);
        k_fin1_gemm2<<<NB_N, 256, 0, stream>>>(b1, W2, deg, fh1, x1, fh2);
        k_scatter2<<<(N_EDGES * NCLS + 255) / 256, 256, 0, stream>>>(ei, ew, flag, deg, fh2, agg2);
        k_final  <<<NB_N, 256, 0, stream>>>(agg2, fh2, deg, b2, lsm);
    }
}

// Round 11
// 280.806 us; speedup vs baseline: 1.1562x; 1.1561x over previous
//
#include <hip/hip_runtime.h>

#define N_NODES 100000
#define N_EDGES 3200000
#define D_FEAT  512
#define HIDDEN  16
#define NCLS    6
#define BSH     7                      // bucket = col >> 7
#define BNODES  128                    // nodes per bucket
#define NBUK    782                    // ceil(N_NODES/128)
#define BCAP    6144                   // LDS bucket capacity (avg 4092, +32 sigma)
#define NBLK_A  512                    // build blocks: exactly 2 per CU
#define TILE    6250                   // ceil(N_EDGES/NBLK_A)

typedef __attribute__((ext_vector_type(8))) short bf16x8;
typedef __attribute__((ext_vector_type(4))) float f32x4;

// ---------- helpers ----------

__device__ __forceinline__ int eidx(const int* __restrict__ ei, int is64, int pos) {
    return is64 ? ei[2 * (long long)pos] : ei[pos];
}

__global__ void k_detect(const int* __restrict__ ei, int* __restrict__ flag) {
    int v = ei[2 * threadIdx.x + 1];
    unsigned long long b = __ballot(v != 0);
    if (threadIdx.x == 0) flag[0] = (b == 0ULL) ? 1 : 0;
}

__device__ __forceinline__ unsigned short f2bf(float f) {     // RNE f32->bf16
    unsigned u = __float_as_uint(f);
    return (unsigned short)((u + 0x7FFFu + ((u >> 16) & 1u)) >> 16);
}

// ---------- bucket build ----------

__global__ __launch_bounds__(256)
void k_bhist(const int* __restrict__ ei, const int* __restrict__ flag,
             int* __restrict__ bcnt) {
    __shared__ int lh[NBUK];
    for (int i = threadIdx.x; i < NBUK; i += 256) lh[i] = 0;
    __syncthreads();
    int is64 = flag[0];
    int s = blockIdx.x * TILE, e1 = min(s + TILE, N_EDGES);
    for (int e = s + threadIdx.x; e < e1; e += 256) {
        int c = eidx(ei, is64, N_EDGES + e);
        atomicAdd(&lh[c >> BSH], 1);
    }
    __syncthreads();
    for (int i = threadIdx.x; i < NBUK; i += 256)
        if (lh[i]) atomicAdd(&bcnt[i], lh[i]);
}

__global__ void k_bscan(const int* __restrict__ bcnt, int* __restrict__ bstart,
                        int* __restrict__ bcursor) {
    __shared__ int s[1024];
    int t = threadIdx.x;
    int v = (t < NBUK) ? bcnt[t] : 0;
    s[t] = v;
    __syncthreads();
    for (int off = 1; off < 1024; off <<= 1) {
        int u = (t >= off) ? s[t - off] : 0;
        __syncthreads();
        s[t] += u;
        __syncthreads();
    }
    int excl = s[t] - v;
    if (t <= NBUK) bstart[t] = excl;
    if (t < NBUK)  bcursor[t] = excl;
}

// scatter edges into bucket-major abuf with block-reserved runs
// pack: x = row | (col&127)<<17  (row < 2^17), y = bits(w)
__global__ __launch_bounds__(256)
void k_bscat(const int* __restrict__ ei, const float* __restrict__ ew,
             const int* __restrict__ flag, int* __restrict__ bcursor,
             uint2* __restrict__ abuf) {
    __shared__ int lh[NBUK];
    __shared__ int lbase[NBUK];
    __shared__ int lcur[NBUK];
    for (int i = threadIdx.x; i < NBUK; i += 256) { lh[i] = 0; lcur[i] = 0; }
    __syncthreads();
    int is64 = flag[0];
    int s = blockIdx.x * TILE, e1 = min(s + TILE, N_EDGES);
    for (int e = s + threadIdx.x; e < e1; e += 256) {
        int c = eidx(ei, is64, N_EDGES + e);
        atomicAdd(&lh[c >> BSH], 1);
    }
    __syncthreads();
    for (int i = threadIdx.x; i < NBUK; i += 256)
        if (lh[i]) lbase[i] = atomicAdd(&bcursor[i], lh[i]);
    __syncthreads();
    for (int e = s + threadIdx.x; e < e1; e += 256) {
        int r = eidx(ei, is64, e);
        int c = eidx(ei, is64, N_EDGES + e);
        float w = ew[e];
        int b = c >> BSH;
        int off = atomicAdd(&lcur[b], 1);
        abuf[lbase[b] + off] = make_uint2((unsigned)r | ((unsigned)(c & (BNODES - 1)) << 17),
                                          __float_as_uint(w));
    }
}

// per-bucket counting sort (LDS-staged): abuf -> eperm {row, raw w};
// emits startA and dinv (cnt+wsum fused, single abuf read).
__global__ __launch_bounds__(256)
void k_bsort(const int* __restrict__ bstart, const uint2* __restrict__ abuf,
             uint2* __restrict__ eperm, int* __restrict__ startA,
             float* __restrict__ dinv) {
    __shared__ uint2 se[BCAP];                     // 48 KB
    __shared__ int   cnt[BNODES];
    __shared__ int   scn[256];
    __shared__ int   cur[BNODES];
    __shared__ float wsum[BNODES];
    int t = threadIdx.x, b = blockIdx.x;
    int s0 = bstart[b], s1 = bstart[b + 1];
    int nb = s1 - s0;
    if (t < BNODES) { cnt[t] = 0; wsum[t] = 0.0f; }
    __syncthreads();

    bool fits = (nb <= BCAP);
    if (fits) {
        for (int k = t; k < nb; k += 256) {
            uint2 a = abuf[s0 + k];
            se[k] = a;
            int ln = (int)(a.x >> 17);
            atomicAdd(&cnt[ln], 1);
            atomicAdd(&wsum[ln], __uint_as_float(a.y));
        }
    } else {
        for (int k = t; k < nb; k += 256) {
            uint2 a = abuf[s0 + k];
            int ln = (int)(a.x >> 17);
            atomicAdd(&cnt[ln], 1);
            atomicAdd(&wsum[ln], __uint_as_float(a.y));
        }
    }
    __syncthreads();
    int v = (t < BNODES) ? cnt[t] : 0;
    scn[t] = v;
    __syncthreads();
    for (int off = 1; off < 256; off <<= 1) {
        int u = (t >= off) ? scn[t - off] : 0;
        __syncthreads();
        scn[t] += u;
        __syncthreads();
    }
    int excl = scn[t] - v;
    if (t < BNODES) {
        cur[t] = excl;
        int node = b * BNODES + t;
        if (node <= N_NODES) startA[node] = s0 + excl;
        if (node <  N_NODES) dinv[node] = rsqrtf(1.0f + wsum[t]);
    }
    __syncthreads();
    if (fits) {
        for (int k = t; k < nb; k += 256) {
            uint2 a = se[k];
            int ln = (int)(a.x >> 17);
            int off = atomicAdd(&cur[ln], 1);
            eperm[s0 + off] = make_uint2(a.x & 0x1FFFFu, a.y);
        }
    } else {
        for (int k = t; k < nb; k += 256) {
            uint2 a = abuf[s0 + k];
            int ln = (int)(a.x >> 17);
            int off = atomicAdd(&cur[ln], 1);
            eperm[s0 + off] = make_uint2(a.x & 0x1FFFFu, a.y);
        }
    }
}

// ---------- layer 1 transform: h1 = x @ W1 via MFMA (bf16 out) ----------
// One wave per 16-row tile; 4 waves/block -> 64 rows/block, 1563 blocks.
// B-frags (ALL of W1, bf16) live in 64 VGPRs for the whole kernel: zero
// per-iteration W1 traffic (the R9/R10 kernel stalled on per-k uniform W1
// loads). A-frags load straight from global (2 float4/lane/step, full-line
// coalescing), convert f32->bf16 inline. No LDS, no barriers; HBM-bound.
// Layouts (m89-verified family): A/B lane L -> m/n=L&15, k=(L>>4)*8+i;
// C/D lane L reg r -> row=(L>>4)*4+r, col=L&15.

__global__ __launch_bounds__(256, 2)
void k_gemm1(const float* __restrict__ x, const float* __restrict__ W1g,
             unsigned short* __restrict__ h1b) {
    const int t   = threadIdx.x;
    const int wid = t >> 6;
    const int L   = t & 63;
    const int lm  = L & 15;
    const int lk  = L >> 4;
    const int row0 = blockIdx.x * 64 + wid * 16;
    const int grow = min(row0 + lm, N_NODES - 1);

    // preload all B-frags: bw[s][i] = bf16(W1[s*32 + lk*8 + i][lm])
    bf16x8 bw[16];
#pragma unroll
    for (int s = 0; s < 16; ++s) {
#pragma unroll
        for (int i = 0; i < 8; ++i) {
            int k = s * 32 + lk * 8 + i;
            bw[s][i] = (short)f2bf(W1g[k * 16 + lm]);
        }
    }

    f32x4 acc = {0.0f, 0.0f, 0.0f, 0.0f};
    const float* xr = x + (size_t)grow * D_FEAT + lk * 8;

    float4 c0 = *(const float4*)(xr + 0);
    float4 c1 = *(const float4*)(xr + 4);
#pragma unroll
    for (int s = 0; s < 16; ++s) {
        float4 n0 = c0, n1 = c1;
        if (s < 15) {
            n0 = *(const float4*)(xr + (s + 1) * 32 + 0);
            n1 = *(const float4*)(xr + (s + 1) * 32 + 4);
        }
        bf16x8 af;
        af[0] = (short)f2bf(c0.x); af[1] = (short)f2bf(c0.y);
        af[2] = (short)f2bf(c0.z); af[3] = (short)f2bf(c0.w);
        af[4] = (short)f2bf(c1.x); af[5] = (short)f2bf(c1.y);
        af[6] = (short)f2bf(c1.z); af[7] = (short)f2bf(c1.w);
        acc = __builtin_amdgcn_mfma_f32_16x16x32_bf16(af, bw[s], acc, 0, 0, 0);
        c0 = n0; c1 = n1;
    }

#pragma unroll
    for (int r = 0; r < 4; ++r) {
        int orow = row0 + lk * 4 + r;
        if (orow < N_NODES)
            h1b[(size_t)orow * HIDDEN + lm] = f2bf(acc[r]);
    }
}

// ---------- gather layer 1 (+ bias + self-loop) fused with gemm2 ----------
// 16 lanes/node = 4 es x 4 fs; h1 in bf16 (8B/lane); dinv[r] inline;
// unroll-2 dual accumulators.

__global__ __launch_bounds__(256)
void k_gather1(const int* __restrict__ startA, const uint2* __restrict__ ep,
               const float* __restrict__ dinv, const unsigned short* __restrict__ h1b,
               const float* __restrict__ b1, const float* __restrict__ W2g,
               float* __restrict__ x1, float* __restrict__ h2p) {
    __shared__ float sW2[HIDDEN * NCLS];
    __shared__ float sv[16][HIDDEN + 1];
    int t = threadIdx.x;
    if (t < HIDDEN * NCLS) sW2[t] = W2g[t];
    int ln = t >> 4, es = (t >> 2) & 3, fs = t & 3;
    int i = blockIdx.x * 16 + ln;
    bool act = (i < N_NODES);
    float4 a = make_float4(0.0f, 0.0f, 0.0f, 0.0f);
    float4 b = make_float4(0.0f, 0.0f, 0.0f, 0.0f);
    if (act) {
        int s0 = startA[i], n = startA[i + 1] - s0;
        int k = es;
        for (; k + 4 < n; k += 8) {
            uint2 e0 = ep[s0 + k];
            uint2 e1 = ep[s0 + k + 4];
            int r0 = (int)e0.x, r1 = (int)e1.x;
            float w0 = __uint_as_float(e0.y) * dinv[r0];
            float w1 = __uint_as_float(e1.y) * dinv[r1];
            uint2 p0 = *(const uint2*)(h1b + ((size_t)r0 << 4) + 4 * fs);
            uint2 p1 = *(const uint2*)(h1b + ((size_t)r1 << 4) + 4 * fs);
            a.x = fmaf(w0, __uint_as_float(p0.x << 16),          a.x);
            a.y = fmaf(w0, __uint_as_float(p0.x & 0xFFFF0000u),  a.y);
            a.z = fmaf(w0, __uint_as_float(p0.y << 16),          a.z);
            a.w = fmaf(w0, __uint_as_float(p0.y & 0xFFFF0000u),  a.w);
            b.x = fmaf(w1, __uint_as_float(p1.x << 16),          b.x);
            b.y = fmaf(w1, __uint_as_float(p1.x & 0xFFFF0000u),  b.y);
            b.z = fmaf(w1, __uint_as_float(p1.y << 16),          b.z);
            b.w = fmaf(w1, __uint_as_float(p1.y & 0xFFFF0000u),  b.w);
        }
        if (k < n) {
            uint2 e0 = ep[s0 + k];
            int r0 = (int)e0.x;
            float w0 = __uint_as_float(e0.y) * dinv[r0];
            uint2 p0 = *(const uint2*)(h1b + ((size_t)r0 << 4) + 4 * fs);
            a.x = fmaf(w0, __uint_as_float(p0.x << 16),          a.x);
            a.y = fmaf(w0, __uint_as_float(p0.x & 0xFFFF0000u),  a.y);
            a.z = fmaf(w0, __uint_as_float(p0.y << 16),          a.z);
            a.w = fmaf(w0, __uint_as_float(p0.y & 0xFFFF0000u),  a.w);
        }
    }
    a.x += b.x; a.y += b.y; a.z += b.z; a.w += b.w;
    a.x += __shfl_xor(a.x, 4); a.y += __shfl_xor(a.y, 4);
    a.z += __shfl_xor(a.z, 4); a.w += __shfl_xor(a.w, 4);
    a.x += __shfl_xor(a.x, 8); a.y += __shfl_xor(a.y, 8);
    a.z += __shfl_xor(a.z, 8); a.w += __shfl_xor(a.w, 8);
    if (act && es == 0) {
        float di = dinv[i], d2 = di * di;
        uint2 ps = *(const uint2*)(h1b + ((size_t)i << 4) + 4 * fs);
        const float* b1r = b1 + 4 * fs;
        float v0 = di * a.x + d2 * __uint_as_float(ps.x << 16)         + b1r[0];
        float v1 = di * a.y + d2 * __uint_as_float(ps.x & 0xFFFF0000u) + b1r[1];
        float v2 = di * a.z + d2 * __uint_as_float(ps.y << 16)         + b1r[2];
        float v3 = di * a.w + d2 * __uint_as_float(ps.y & 0xFFFF0000u) + b1r[3];
        *(float4*)(x1 + (size_t)i * HIDDEN + 4 * fs) = make_float4(v0, v1, v2, v3);
        sv[ln][4 * fs + 0] = v0; sv[ln][4 * fs + 1] = v1;
        sv[ln][4 * fs + 2] = v2; sv[ln][4 * fs + 3] = v3;
    }
    __syncthreads();
    int j = t & 15;
    if (act && j < 8) {
        float acc2 = 0.0f;
        if (j < NCLS) {
#pragma unroll
            for (int kk = 0; kk < HIDDEN; ++kk)
                acc2 = fmaf(sv[ln][kk], sW2[kk * NCLS + j], acc2);
        }
        h2p[(size_t)i * 8 + j] = acc2;             // cols 6,7 = 0 pad
    }
}

// ---------- gather layer 2 fused with log_softmax ----------
// 16 lanes/node = 8 es x 2 fs on padded f32 h2p[N,8]; dinv[r] inline.

__global__ __launch_bounds__(256)
void k_gather2(const int* __restrict__ startA, const uint2* __restrict__ ep,
               const float* __restrict__ dinv, const float* __restrict__ h2p,
               const float* __restrict__ b2, float* __restrict__ out) {
    __shared__ float sv[16][9];
    int t = threadIdx.x;
    int ln = t >> 4, es = (t >> 1) & 7, fs = t & 1;
    int i = blockIdx.x * 16 + ln;
    bool act = (i < N_NODES);
    float4 a = make_float4(0.0f, 0.0f, 0.0f, 0.0f);
    float4 b = make_float4(0.0f, 0.0f, 0.0f, 0.0f);
    if (act) {
        int s0 = startA[i], n = startA[i + 1] - s0;
        int k = es;
        for (; k + 8 < n; k += 16) {
            uint2 e0 = ep[s0 + k];
            uint2 e1 = ep[s0 + k + 8];
            int r0 = (int)e0.x, r1 = (int)e1.x;
            float w0 = __uint_as_float(e0.y) * dinv[r0];
            float w1 = __uint_as_float(e1.y) * dinv[r1];
            float4 h0 = *(const float4*)(h2p + ((size_t)r0 << 3) + 4 * fs);
            float4 h8 = *(const float4*)(h2p + ((size_t)r1 << 3) + 4 * fs);
            a.x = fmaf(w0, h0.x, a.x); a.y = fmaf(w0, h0.y, a.y);
            a.z = fmaf(w0, h0.z, a.z); a.w = fmaf(w0, h0.w, a.w);
            b.x = fmaf(w1, h8.x, b.x); b.y = fmaf(w1, h8.y, b.y);
            b.z = fmaf(w1, h8.z, b.z); b.w = fmaf(w1, h8.w, b.w);
        }
        if (k < n) {
            uint2 e0 = ep[s0 + k];
            int r0 = (int)e0.x;
            float w0 = __uint_as_float(e0.y) * dinv[r0];
            float4 h0 = *(const float4*)(h2p + ((size_t)r0 << 3) + 4 * fs);
            a.x = fmaf(w0, h0.x, a.x); a.y = fmaf(w0, h0.y, a.y);
            a.z = fmaf(w0, h0.z, a.z); a.w = fmaf(w0, h0.w, a.w);
        }
    }
    a.x += b.x; a.y += b.y; a.z += b.z; a.w += b.w;
    a.x += __shfl_xor(a.x, 2); a.y += __shfl_xor(a.y, 2);
    a.z += __shfl_xor(a.z, 2); a.w += __shfl_xor(a.w, 2);
    a.x += __shfl_xor(a.x, 4); a.y += __shfl_xor(a.y, 4);
    a.z += __shfl_xor(a.z, 4); a.w += __shfl_xor(a.w, 4);
    a.x += __shfl_xor(a.x, 8); a.y += __shfl_xor(a.y, 8);
    a.z += __shfl_xor(a.z, 8); a.w += __shfl_xor(a.w, 8);
    if (act && es == 0) {
        float di = dinv[i], d2 = di * di;
        const float* hr = h2p + (size_t)i * 8 + 4 * fs;
        int c0 = 4 * fs;
        float v0 = di * a.x + d2 * hr[0] + ((c0 + 0) < NCLS ? b2[c0 + 0] : 0.0f);
        float v1 = di * a.y + d2 * hr[1] + ((c0 + 1) < NCLS ? b2[c0 + 1] : 0.0f);
        float v2 = di * a.z + d2 * hr[2] + ((c0 + 2) < NCLS ? b2[c0 + 2] : 0.0f);
        float v3 = di * a.w + d2 * hr[3] + ((c0 + 3) < NCLS ? b2[c0 + 3] : 0.0f);
        sv[ln][c0 + 0] = v0; sv[ln][c0 + 1] = v1;
        sv[ln][c0 + 2] = v2; sv[ln][c0 + 3] = v3;
    }
    __syncthreads();
    int j = t & 15;
    if (act && j < NCLS) {
        float m = -1e30f;
#pragma unroll
        for (int c = 0; c < NCLS; ++c) m = fmaxf(m, sv[ln][c]);
        float ssum = 0.0f;
#pragma unroll
        for (int c = 0; c < NCLS; ++c) ssum += __expf(sv[ln][c] - m);
        out[(size_t)i * NCLS + j] = sv[ln][j] - m - __logf(ssum);
    }
}

// ---------- tier-3 atomic fallback kernels (small ws) ----------

__global__ void k_initdeg(float* __restrict__ deg) {
    int i = blockIdx.x * 256 + threadIdx.x;
    if (i < N_NODES) deg[i] = 1.0f;
}

__global__ void k_degacc(const int* __restrict__ ei, const float* __restrict__ w,
                         const int* __restrict__ flag, float* __restrict__ deg) {
    int e = blockIdx.x * 256 + threadIdx.x;
    if (e >= N_EDGES) return;
    int c = eidx(ei, flag[0], N_EDGES + e);
    atomicAdd(&deg[c], w[e]);
}

__global__ void k_dinv(float* __restrict__ deg) {
    int i = blockIdx.x * 256 + threadIdx.x;
    if (i < N_NODES) {
        float d = deg[i];
        deg[i] = (d > 0.0f) ? rsqrtf(d) : 0.0f;
    }
}

__global__ __launch_bounds__(256)
void k_gemm1f(const float* __restrict__ x, const float* __restrict__ W1g,
              float* __restrict__ h1) {
    __shared__ float w1s[D_FEAT * HIDDEN];
    for (int p = threadIdx.x; p < D_FEAT * HIDDEN; p += 256) w1s[p] = W1g[p];
    __syncthreads();
    const int total = N_NODES * HIDDEN;
    for (int t = blockIdx.x * 256 + threadIdx.x; t < total; t += gridDim.x * 256) {
        int i = t >> 4, j = t & 15;
        const float4* xr = (const float4*)(x + (size_t)i * D_FEAT);
        float acc = 0.0f;
#pragma unroll 4
        for (int k4 = 0; k4 < D_FEAT / 4; ++k4) {
            float4 xv = xr[k4];
            int kb = (k4 << 6) + j;
            acc = fmaf(xv.x, w1s[kb],      acc);
            acc = fmaf(xv.y, w1s[kb + 16], acc);
            acc = fmaf(xv.z, w1s[kb + 32], acc);
            acc = fmaf(xv.w, w1s[kb + 48], acc);
        }
        h1[t] = acc;
    }
}

__global__ __launch_bounds__(256)
void k_scatter1(const int* __restrict__ ei, const float* __restrict__ w,
                const int* __restrict__ flag, const float* __restrict__ dinv,
                const float* __restrict__ h1, float* __restrict__ agg1) {
    int t = blockIdx.x * 256 + threadIdx.x;
    if (t >= N_EDGES * HIDDEN) return;
    int e = t >> 4, j = t & 15;
    int is64 = flag[0];
    int r = eidx(ei, is64, e);
    int c = eidx(ei, is64, N_EDGES + e);
    float nrm = dinv[r] * w[e] * dinv[c];
    atomicAdd(&agg1[(size_t)c * HIDDEN + j], nrm * h1[(size_t)r * HIDDEN + j]);
}

__global__ void k_fin1_gemm2(const float* __restrict__ b1, const float* __restrict__ W2,
                             const float* __restrict__ dinv, const float* __restrict__ h1,
                             float* __restrict__ x1, float* __restrict__ h2) {
    int i = blockIdx.x * 256 + threadIdx.x;
    if (i >= N_NODES) return;
    float d2 = dinv[i] * dinv[i];
    float v[HIDDEN];
#pragma unroll
    for (int k = 0; k < HIDDEN; ++k)
        v[k] = x1[(size_t)i * HIDDEN + k] + d2 * h1[(size_t)i * HIDDEN + k] + b1[k];
#pragma unroll
    for (int k = 0; k < HIDDEN; ++k)
        x1[(size_t)i * HIDDEN + k] = v[k];
#pragma unroll
    for (int j = 0; j < NCLS; ++j) {
        float a = 0.0f;
#pragma unroll
        for (int k = 0; k < HIDDEN; ++k) a = fmaf(v[k], W2[k * NCLS + j], a);
        h2[(size_t)i * NCLS + j] = a;
    }
}

__global__ __launch_bounds__(256)
void k_scatter2(const int* __restrict__ ei, const float* __restrict__ w,
                const int* __restrict__ flag, const float* __restrict__ dinv,
                const float* __restrict__ h2, float* __restrict__ agg2) {
    int t = blockIdx.x * 256 + threadIdx.x;
    if (t >= N_EDGES * NCLS) return;
    int e = t / NCLS, j = t - e * NCLS;
    int is64 = flag[0];
    int r = eidx(ei, is64, e);
    int c = eidx(ei, is64, N_EDGES + e);
    float nrm = dinv[r] * w[e] * dinv[c];
    atomicAdd(&agg2[(size_t)c * NCLS + j], nrm * h2[(size_t)r * NCLS + j]);
}

__global__ void k_final(const float* __restrict__ agg2, const float* __restrict__ h2,
                        const float* __restrict__ dinv, const float* __restrict__ b2,
                        float* __restrict__ out) {
    int i = blockIdx.x * 256 + threadIdx.x;
    if (i >= N_NODES) return;
    float d2 = dinv[i] * dinv[i];
    float v[NCLS];
    float m = -1e30f;
#pragma unroll
    for (int j = 0; j < NCLS; ++j) {
        v[j] = agg2[(size_t)i * NCLS + j] + d2 * h2[(size_t)i * NCLS + j] + b2[j];
        m = fmaxf(m, v[j]);
    }
    float s = 0.0f;
#pragma unroll
    for (int j = 0; j < NCLS; ++j) s += __expf(v[j] - m);
    float l = __logf(s);
#pragma unroll
    for (int j = 0; j < NCLS; ++j) out[(size_t)i * NCLS + j] = v[j] - m - l;
}

// ---------- launch ----------

extern "C" void kernel_launch(void* const* d_in, const int* in_sizes, int n_in,
                              void* d_out, int out_size, void* d_ws, size_t ws_size,
                              hipStream_t stream) {
    const float* x  = (const float*)d_in[0];
    const float* W1 = (const float*)d_in[1];
    const float* b1 = (const float*)d_in[2];
    const float* W2 = (const float*)d_in[3];
    const float* b2 = (const float*)d_in[4];
    const float* ew = (const float*)d_in[5];
    const int*   ei = (const int*)d_in[6];

    float* out = (float*)d_out;
    float* lsm = out;                               // [N, 6]
    float* x1  = out + (size_t)N_NODES * NCLS;      // [N, 16]

    const int NB_N = (N_NODES + 255) / 256;         // 391
    const int NB_E = (N_EDGES + 255) / 256;

    float* W    = (float*)d_ws;
    int*   flag = (int*)d_ws;

    // ---- tier-1 layout (4B words) ----
    int*   bcnt    = (int*)(W + 256);        // 783
    int*   bstart  = (int*)(W + 1152);       // 783
    int*   bcursor = (int*)(W + 2048);       // 782
    int*   startA  = (int*)(W + 2944);       // 100001 -> ends 102945
    float* dinvB   = W + 102948;             // 100000 -> ends 202948
    uint2* abuf    = (uint2*)(W + 202948);   // 3.2M uint2 -> ends 6602948; aliased:
    unsigned short* h1b = (unsigned short*)(W + 202948);  // 1.6M bf16 = 800K words
    float* h2p     = W + 1802948;            //   800K padded f32 [N,8]
    uint2* eperm   = (uint2*)(W + 6602948);  // 3.2M uint2 -> ends 13002948
    const size_t NEED = (size_t)13002948 * 4;       // ~52.0 MB

    if (ws_size >= NEED) {
        hipMemsetAsync(bcnt, 0, (NBUK + 1) * 4, stream);
        k_detect<<<1, 64, 0, stream>>>(ei, flag);
        k_bhist <<<NBLK_A, 256, 0, stream>>>(ei, flag, bcnt);
        k_bscan <<<1, 1024, 0, stream>>>(bcnt, bstart, bcursor);
        k_bscat <<<NBLK_A, 256, 0, stream>>>(ei, ew, flag, bcursor, abuf);
        k_bsort <<<NBUK, 256, 0, stream>>>(bstart, abuf, eperm, startA, dinvB);
        k_gemm1 <<<(N_NODES + 63) / 64, 256, 0, stream>>>(x, W1, h1b);
        k_gather1<<<(N_NODES + 15) / 16, 256, 0, stream>>>(startA, eperm, dinvB, h1b,
                                                           b1, W2, x1, h2p);
        k_gather2<<<(N_NODES + 15) / 16, 256, 0, stream>>>(startA, eperm, dinvB, h2p,
                                                           b2, lsm);
    } else {
        float* deg  = W + 1024;
        float* fh1  = W + 101376;
        float* fh2  = fh1 + (size_t)N_NODES * HIDDEN;
        float* agg2 = fh2 + (size_t)N_NODES * NCLS;
        hipMemsetAsync(x1,   0, (size_t)N_NODES * HIDDEN * sizeof(float), stream);
        hipMemsetAsync(agg2, 0, (size_t)N_NODES * NCLS   * sizeof(float), stream);
        k_detect <<<1, 64, 0, stream>>>(ei, flag);
        k_initdeg<<<NB_N, 256, 0, stream>>>(deg);
        k_degacc <<<NB_E, 256, 0, stream>>>(ei, ew, flag, deg);
        k_dinv   <<<NB_N, 256, 0, stream>>>(deg);
        k_gemm1f <<<2048, 256, 0, stream>>>(x, W1, fh1);
        k_scatter1<<<(N_EDGES * HIDDEN + 255) / 256, 256, 0, stream>>>(ei, ew, flag, deg, fh1, x1);
        k_fin1_gemm2<<<NB_N, 256, 0, stream>>>(b1, W2, deg, fh1, x1, fh2);
        k_scatter2<<<(N_EDGES * NCLS + 255) / 256, 256, 0, stream>>>(ei, ew, flag, deg, fh2, agg2);
        k_final  <<<NB_N, 256, 0, stream>>>(agg2, fh2, deg, b2, lsm);
    }
}

// Round 12
// 271.892 us; speedup vs baseline: 1.1941x; 1.0328x over previous
//
#include <hip/hip_runtime.h>

#define N_NODES 100000
#define N_EDGES 3200000
#define D_FEAT  512
#define HIDDEN  16
#define NCLS    6
#define BSH     7                      // bucket = col >> 7
#define BNODES  128                    // nodes per bucket
#define NBUK    782                    // ceil(N_NODES/128)
#define BCAP    6144                   // LDS bucket capacity (avg 4092, +32 sigma)
#define NBLK_A  512                    // build blocks: exactly 2 per CU
#define TILE    6250                   // ceil(N_EDGES/NBLK_A)

typedef __attribute__((ext_vector_type(8))) short bf16x8;
typedef __attribute__((ext_vector_type(4))) float f32x4;

// ---------- helpers ----------

__device__ __forceinline__ int eidx(const int* __restrict__ ei, int is64, int pos) {
    return is64 ? ei[2 * (long long)pos] : ei[pos];
}

__global__ void k_detect(const int* __restrict__ ei, int* __restrict__ flag) {
    int v = ei[2 * threadIdx.x + 1];
    unsigned long long b = __ballot(v != 0);
    if (threadIdx.x == 0) flag[0] = (b == 0ULL) ? 1 : 0;
}

__device__ __forceinline__ unsigned short f2bf(float f) {     // RNE f32->bf16
    unsigned u = __float_as_uint(f);
    return (unsigned short)((u + 0x7FFFu + ((u >> 16) & 1u)) >> 16);
}

// ---------- bucket build ----------

__global__ __launch_bounds__(256)
void k_bhist(const int* __restrict__ ei, const int* __restrict__ flag,
             int* __restrict__ bcnt) {
    __shared__ int lh[NBUK];
    for (int i = threadIdx.x; i < NBUK; i += 256) lh[i] = 0;
    __syncthreads();
    int is64 = flag[0];
    int s = blockIdx.x * TILE, e1 = min(s + TILE, N_EDGES);
    for (int e = s + threadIdx.x; e < e1; e += 256) {
        int c = eidx(ei, is64, N_EDGES + e);
        atomicAdd(&lh[c >> BSH], 1);
    }
    __syncthreads();
    for (int i = threadIdx.x; i < NBUK; i += 256)
        if (lh[i]) atomicAdd(&bcnt[i], lh[i]);
}

__global__ void k_bscan(const int* __restrict__ bcnt, int* __restrict__ bstart,
                        int* __restrict__ bcursor) {
    __shared__ int s[1024];
    int t = threadIdx.x;
    int v = (t < NBUK) ? bcnt[t] : 0;
    s[t] = v;
    __syncthreads();
    for (int off = 1; off < 1024; off <<= 1) {
        int u = (t >= off) ? s[t - off] : 0;
        __syncthreads();
        s[t] += u;
        __syncthreads();
    }
    int excl = s[t] - v;
    if (t <= NBUK) bstart[t] = excl;
    if (t < NBUK)  bcursor[t] = excl;
}

// scatter edges into bucket-major abuf with block-reserved runs
// pack: x = row | (col&127)<<17  (row < 2^17), y = bits(w)
__global__ __launch_bounds__(256)
void k_bscat(const int* __restrict__ ei, const float* __restrict__ ew,
             const int* __restrict__ flag, int* __restrict__ bcursor,
             uint2* __restrict__ abuf) {
    __shared__ int lh[NBUK];
    __shared__ int lbase[NBUK];
    __shared__ int lcur[NBUK];
    for (int i = threadIdx.x; i < NBUK; i += 256) { lh[i] = 0; lcur[i] = 0; }
    __syncthreads();
    int is64 = flag[0];
    int s = blockIdx.x * TILE, e1 = min(s + TILE, N_EDGES);
    for (int e = s + threadIdx.x; e < e1; e += 256) {
        int c = eidx(ei, is64, N_EDGES + e);
        atomicAdd(&lh[c >> BSH], 1);
    }
    __syncthreads();
    for (int i = threadIdx.x; i < NBUK; i += 256)
        if (lh[i]) lbase[i] = atomicAdd(&bcursor[i], lh[i]);
    __syncthreads();
    for (int e = s + threadIdx.x; e < e1; e += 256) {
        int r = eidx(ei, is64, e);
        int c = eidx(ei, is64, N_EDGES + e);
        float w = ew[e];
        int b = c >> BSH;
        int off = atomicAdd(&lcur[b], 1);
        abuf[lbase[b] + off] = make_uint2((unsigned)r | ((unsigned)(c & (BNODES - 1)) << 17),
                                          __float_as_uint(w));
    }
}

// per-bucket counting sort (LDS-staged): abuf -> eperm {row, raw w};
// emits startA and dinv (cnt+wsum fused, single abuf read).
__global__ __launch_bounds__(256)
void k_bsort(const int* __restrict__ bstart, const uint2* __restrict__ abuf,
             uint2* __restrict__ eperm, int* __restrict__ startA,
             float* __restrict__ dinv) {
    __shared__ uint2 se[BCAP];                     // 48 KB
    __shared__ int   cnt[BNODES];
    __shared__ int   scn[256];
    __shared__ int   cur[BNODES];
    __shared__ float wsum[BNODES];
    int t = threadIdx.x, b = blockIdx.x;
    int s0 = bstart[b], s1 = bstart[b + 1];
    int nb = s1 - s0;
    if (t < BNODES) { cnt[t] = 0; wsum[t] = 0.0f; }
    __syncthreads();

    bool fits = (nb <= BCAP);
    if (fits) {
        for (int k = t; k < nb; k += 256) {
            uint2 a = abuf[s0 + k];
            se[k] = a;
            int ln = (int)(a.x >> 17);
            atomicAdd(&cnt[ln], 1);
            atomicAdd(&wsum[ln], __uint_as_float(a.y));
        }
    } else {
        for (int k = t; k < nb; k += 256) {
            uint2 a = abuf[s0 + k];
            int ln = (int)(a.x >> 17);
            atomicAdd(&cnt[ln], 1);
            atomicAdd(&wsum[ln], __uint_as_float(a.y));
        }
    }
    __syncthreads();
    int v = (t < BNODES) ? cnt[t] : 0;
    scn[t] = v;
    __syncthreads();
    for (int off = 1; off < 256; off <<= 1) {
        int u = (t >= off) ? scn[t - off] : 0;
        __syncthreads();
        scn[t] += u;
        __syncthreads();
    }
    int excl = scn[t] - v;
    if (t < BNODES) {
        cur[t] = excl;
        int node = b * BNODES + t;
        if (node <= N_NODES) startA[node] = s0 + excl;
        if (node <  N_NODES) dinv[node] = rsqrtf(1.0f + wsum[t]);
    }
    __syncthreads();
    if (fits) {
        for (int k = t; k < nb; k += 256) {
            uint2 a = se[k];
            int ln = (int)(a.x >> 17);
            int off = atomicAdd(&cur[ln], 1);
            eperm[s0 + off] = make_uint2(a.x & 0x1FFFFu, a.y);
        }
    } else {
        for (int k = t; k < nb; k += 256) {
            uint2 a = abuf[s0 + k];
            int ln = (int)(a.x >> 17);
            int off = atomicAdd(&cur[ln], 1);
            eperm[s0 + off] = make_uint2(a.x & 0x1FFFFu, a.y);
        }
    }
}

// ---------- layer 1 transform: h1 = x @ W1 via MFMA (bf16 out) ----------
// TWO 16-row tiles per wave (share register-resident W1 B-frags): 4 loads in
// flight per step + 2 independent MFMA chains (R11's single-tile version was
// latency-exposed at ~105us: 2 loads/step, serial chain). 4 waves x 2 tiles
// -> 128 rows/block, grid 782. ~120 VGPR -> 4 waves/SIMD.

__global__ __launch_bounds__(256)
void k_gemm1(const float* __restrict__ x, const float* __restrict__ W1g,
             unsigned short* __restrict__ h1b) {
    const int t   = threadIdx.x;
    const int wid = t >> 6;
    const int L   = t & 63;
    const int lm  = L & 15;
    const int lk  = L >> 4;
    const int rowA = blockIdx.x * 128 + wid * 32;
    const int rowB = rowA + 16;
    const int gA = min(rowA + lm, N_NODES - 1);
    const int gB = min(rowB + lm, N_NODES - 1);

    // preload all B-frags: bw[s][i] = bf16(W1[s*32 + lk*8 + i][lm])
    bf16x8 bw[16];
#pragma unroll
    for (int s = 0; s < 16; ++s) {
#pragma unroll
        for (int i = 0; i < 8; ++i) {
            int k = s * 32 + lk * 8 + i;
            bw[s][i] = (short)f2bf(W1g[k * 16 + lm]);
        }
    }

    f32x4 accA = {0.0f, 0.0f, 0.0f, 0.0f};
    f32x4 accB = {0.0f, 0.0f, 0.0f, 0.0f};
    const float* xA = x + (size_t)gA * D_FEAT + lk * 8;
    const float* xB = x + (size_t)gB * D_FEAT + lk * 8;

    float4 a0 = *(const float4*)(xA + 0);
    float4 a1 = *(const float4*)(xA + 4);
    float4 b0 = *(const float4*)(xB + 0);
    float4 b1 = *(const float4*)(xB + 4);
#pragma unroll
    for (int s = 0; s < 16; ++s) {
        float4 nA0 = a0, nA1 = a1, nB0 = b0, nB1 = b1;
        if (s < 15) {
            nA0 = *(const float4*)(xA + (s + 1) * 32 + 0);
            nA1 = *(const float4*)(xA + (s + 1) * 32 + 4);
            nB0 = *(const float4*)(xB + (s + 1) * 32 + 0);
            nB1 = *(const float4*)(xB + (s + 1) * 32 + 4);
        }
        bf16x8 afA, afB;
        afA[0] = (short)f2bf(a0.x); afA[1] = (short)f2bf(a0.y);
        afA[2] = (short)f2bf(a0.z); afA[3] = (short)f2bf(a0.w);
        afA[4] = (short)f2bf(a1.x); afA[5] = (short)f2bf(a1.y);
        afA[6] = (short)f2bf(a1.z); afA[7] = (short)f2bf(a1.w);
        afB[0] = (short)f2bf(b0.x); afB[1] = (short)f2bf(b0.y);
        afB[2] = (short)f2bf(b0.z); afB[3] = (short)f2bf(b0.w);
        afB[4] = (short)f2bf(b1.x); afB[5] = (short)f2bf(b1.y);
        afB[6] = (short)f2bf(b1.z); afB[7] = (short)f2bf(b1.w);
        accA = __builtin_amdgcn_mfma_f32_16x16x32_bf16(afA, bw[s], accA, 0, 0, 0);
        accB = __builtin_amdgcn_mfma_f32_16x16x32_bf16(afB, bw[s], accB, 0, 0, 0);
        a0 = nA0; a1 = nA1; b0 = nB0; b1 = nB1;
    }

#pragma unroll
    for (int r = 0; r < 4; ++r) {
        int oA = rowA + lk * 4 + r;
        int oB = rowB + lk * 4 + r;
        if (oA < N_NODES) h1b[(size_t)oA * HIDDEN + lm] = f2bf(accA[r]);
        if (oB < N_NODES) h1b[(size_t)oB * HIDDEN + lm] = f2bf(accB[r]);
    }
}

// ---------- gather layer 1 (+ bias + self-loop) fused with gemm2 ----------
// 16 lanes/node = 4 es x 4 fs; h1 in bf16 (8B/lane); dinv[r] inline;
// unroll-2 dual accumulators. h2 output in bf16 (padded [N,8]).

__global__ __launch_bounds__(256)
void k_gather1(const int* __restrict__ startA, const uint2* __restrict__ ep,
               const float* __restrict__ dinv, const unsigned short* __restrict__ h1b,
               const float* __restrict__ b1, const float* __restrict__ W2g,
               float* __restrict__ x1, unsigned short* __restrict__ h2b) {
    __shared__ float sW2[HIDDEN * NCLS];
    __shared__ float sv[16][HIDDEN + 1];
    int t = threadIdx.x;
    if (t < HIDDEN * NCLS) sW2[t] = W2g[t];
    int ln = t >> 4, es = (t >> 2) & 3, fs = t & 3;
    int i = blockIdx.x * 16 + ln;
    bool act = (i < N_NODES);
    float4 a = make_float4(0.0f, 0.0f, 0.0f, 0.0f);
    float4 b = make_float4(0.0f, 0.0f, 0.0f, 0.0f);
    if (act) {
        int s0 = startA[i], n = startA[i + 1] - s0;
        int k = es;
        for (; k + 4 < n; k += 8) {
            uint2 e0 = ep[s0 + k];
            uint2 e1 = ep[s0 + k + 4];
            int r0 = (int)e0.x, r1 = (int)e1.x;
            float w0 = __uint_as_float(e0.y) * dinv[r0];
            float w1 = __uint_as_float(e1.y) * dinv[r1];
            uint2 p0 = *(const uint2*)(h1b + ((size_t)r0 << 4) + 4 * fs);
            uint2 p1 = *(const uint2*)(h1b + ((size_t)r1 << 4) + 4 * fs);
            a.x = fmaf(w0, __uint_as_float(p0.x << 16),          a.x);
            a.y = fmaf(w0, __uint_as_float(p0.x & 0xFFFF0000u),  a.y);
            a.z = fmaf(w0, __uint_as_float(p0.y << 16),          a.z);
            a.w = fmaf(w0, __uint_as_float(p0.y & 0xFFFF0000u),  a.w);
            b.x = fmaf(w1, __uint_as_float(p1.x << 16),          b.x);
            b.y = fmaf(w1, __uint_as_float(p1.x & 0xFFFF0000u),  b.y);
            b.z = fmaf(w1, __uint_as_float(p1.y << 16),          b.z);
            b.w = fmaf(w1, __uint_as_float(p1.y & 0xFFFF0000u),  b.w);
        }
        if (k < n) {
            uint2 e0 = ep[s0 + k];
            int r0 = (int)e0.x;
            float w0 = __uint_as_float(e0.y) * dinv[r0];
            uint2 p0 = *(const uint2*)(h1b + ((size_t)r0 << 4) + 4 * fs);
            a.x = fmaf(w0, __uint_as_float(p0.x << 16),          a.x);
            a.y = fmaf(w0, __uint_as_float(p0.x & 0xFFFF0000u),  a.y);
            a.z = fmaf(w0, __uint_as_float(p0.y << 16),          a.z);
            a.w = fmaf(w0, __uint_as_float(p0.y & 0xFFFF0000u),  a.w);
        }
    }
    a.x += b.x; a.y += b.y; a.z += b.z; a.w += b.w;
    a.x += __shfl_xor(a.x, 4); a.y += __shfl_xor(a.y, 4);
    a.z += __shfl_xor(a.z, 4); a.w += __shfl_xor(a.w, 4);
    a.x += __shfl_xor(a.x, 8); a.y += __shfl_xor(a.y, 8);
    a.z += __shfl_xor(a.z, 8); a.w += __shfl_xor(a.w, 8);
    if (act && es == 0) {
        float di = dinv[i], d2 = di * di;
        uint2 ps = *(const uint2*)(h1b + ((size_t)i << 4) + 4 * fs);
        const float* b1r = b1 + 4 * fs;
        float v0 = di * a.x + d2 * __uint_as_float(ps.x << 16)         + b1r[0];
        float v1 = di * a.y + d2 * __uint_as_float(ps.x & 0xFFFF0000u) + b1r[1];
        float v2 = di * a.z + d2 * __uint_as_float(ps.y << 16)         + b1r[2];
        float v3 = di * a.w + d2 * __uint_as_float(ps.y & 0xFFFF0000u) + b1r[3];
        *(float4*)(x1 + (size_t)i * HIDDEN + 4 * fs) = make_float4(v0, v1, v2, v3);
        sv[ln][4 * fs + 0] = v0; sv[ln][4 * fs + 1] = v1;
        sv[ln][4 * fs + 2] = v2; sv[ln][4 * fs + 3] = v3;
    }
    __syncthreads();
    int j = t & 15;
    if (act && j < 8) {
        float acc2 = 0.0f;
        if (j < NCLS) {
#pragma unroll
            for (int kk = 0; kk < HIDDEN; ++kk)
                acc2 = fmaf(sv[ln][kk], sW2[kk * NCLS + j], acc2);
        }
        h2b[(size_t)i * 8 + j] = (j < NCLS) ? f2bf(acc2) : (unsigned short)0;
    }
}

// ---------- gather layer 2 fused with log_softmax ----------
// 16 lanes/node = 8 es x 2 fs on padded bf16 h2b[N,8] (8B/lane); dinv inline.

__global__ __launch_bounds__(256)
void k_gather2(const int* __restrict__ startA, const uint2* __restrict__ ep,
               const float* __restrict__ dinv, const unsigned short* __restrict__ h2b,
               const float* __restrict__ b2, float* __restrict__ out) {
    __shared__ float sv[16][9];
    int t = threadIdx.x;
    int ln = t >> 4, es = (t >> 1) & 7, fs = t & 1;
    int i = blockIdx.x * 16 + ln;
    bool act = (i < N_NODES);
    float4 a = make_float4(0.0f, 0.0f, 0.0f, 0.0f);
    float4 b = make_float4(0.0f, 0.0f, 0.0f, 0.0f);
    if (act) {
        int s0 = startA[i], n = startA[i + 1] - s0;
        int k = es;
        for (; k + 8 < n; k += 16) {
            uint2 e0 = ep[s0 + k];
            uint2 e1 = ep[s0 + k + 8];
            int r0 = (int)e0.x, r1 = (int)e1.x;
            float w0 = __uint_as_float(e0.y) * dinv[r0];
            float w1 = __uint_as_float(e1.y) * dinv[r1];
            uint2 p0 = *(const uint2*)(h2b + ((size_t)r0 << 3) + 4 * fs);
            uint2 p1 = *(const uint2*)(h2b + ((size_t)r1 << 3) + 4 * fs);
            a.x = fmaf(w0, __uint_as_float(p0.x << 16),          a.x);
            a.y = fmaf(w0, __uint_as_float(p0.x & 0xFFFF0000u),  a.y);
            a.z = fmaf(w0, __uint_as_float(p0.y << 16),          a.z);
            a.w = fmaf(w0, __uint_as_float(p0.y & 0xFFFF0000u),  a.w);
            b.x = fmaf(w1, __uint_as_float(p1.x << 16),          b.x);
            b.y = fmaf(w1, __uint_as_float(p1.x & 0xFFFF0000u),  b.y);
            b.z = fmaf(w1, __uint_as_float(p1.y << 16),          b.z);
            b.w = fmaf(w1, __uint_as_float(p1.y & 0xFFFF0000u),  b.w);
        }
        if (k < n) {
            uint2 e0 = ep[s0 + k];
            int r0 = (int)e0.x;
            float w0 = __uint_as_float(e0.y) * dinv[r0];
            uint2 p0 = *(const uint2*)(h2b + ((size_t)r0 << 3) + 4 * fs);
            a.x = fmaf(w0, __uint_as_float(p0.x << 16),          a.x);
            a.y = fmaf(w0, __uint_as_float(p0.x & 0xFFFF0000u),  a.y);
            a.z = fmaf(w0, __uint_as_float(p0.y << 16),          a.z);
            a.w = fmaf(w0, __uint_as_float(p0.y & 0xFFFF0000u),  a.w);
        }
    }
    a.x += b.x; a.y += b.y; a.z += b.z; a.w += b.w;
    a.x += __shfl_xor(a.x, 2); a.y += __shfl_xor(a.y, 2);
    a.z += __shfl_xor(a.z, 2); a.w += __shfl_xor(a.w, 2);
    a.x += __shfl_xor(a.x, 4); a.y += __shfl_xor(a.y, 4);
    a.z += __shfl_xor(a.z, 4); a.w += __shfl_xor(a.w, 4);
    a.x += __shfl_xor(a.x, 8); a.y += __shfl_xor(a.y, 8);
    a.z += __shfl_xor(a.z, 8); a.w += __shfl_xor(a.w, 8);
    if (act && es == 0) {
        float di = dinv[i], d2 = di * di;
        uint2 ps = *(const uint2*)(h2b + ((size_t)i << 3) + 4 * fs);
        int c0 = 4 * fs;
        float s0v = __uint_as_float(ps.x << 16);
        float s1v = __uint_as_float(ps.x & 0xFFFF0000u);
        float s2v = __uint_as_float(ps.y << 16);
        float s3v = __uint_as_float(ps.y & 0xFFFF0000u);
        float v0 = di * a.x + d2 * s0v + ((c0 + 0) < NCLS ? b2[c0 + 0] : 0.0f);
        float v1 = di * a.y + d2 * s1v + ((c0 + 1) < NCLS ? b2[c0 + 1] : 0.0f);
        float v2 = di * a.z + d2 * s2v + ((c0 + 2) < NCLS ? b2[c0 + 2] : 0.0f);
        float v3 = di * a.w + d2 * s3v + ((c0 + 3) < NCLS ? b2[c0 + 3] : 0.0f);
        sv[ln][c0 + 0] = v0; sv[ln][c0 + 1] = v1;
        sv[ln][c0 + 2] = v2; sv[ln][c0 + 3] = v3;
    }
    __syncthreads();
    int j = t & 15;
    if (act && j < NCLS) {
        float m = -1e30f;
#pragma unroll
        for (int c = 0; c < NCLS; ++c) m = fmaxf(m, sv[ln][c]);
        float ssum = 0.0f;
#pragma unroll
        for (int c = 0; c < NCLS; ++c) ssum += __expf(sv[ln][c] - m);
        out[(size_t)i * NCLS + j] = sv[ln][j] - m - __logf(ssum);
    }
}

// ---------- tier-3 atomic fallback kernels (small ws) ----------

__global__ void k_initdeg(float* __restrict__ deg) {
    int i = blockIdx.x * 256 + threadIdx.x;
    if (i < N_NODES) deg[i] = 1.0f;
}

__global__ void k_degacc(const int* __restrict__ ei, const float* __restrict__ w,
                         const int* __restrict__ flag, float* __restrict__ deg) {
    int e = blockIdx.x * 256 + threadIdx.x;
    if (e >= N_EDGES) return;
    int c = eidx(ei, flag[0], N_EDGES + e);
    atomicAdd(&deg[c], w[e]);
}

__global__ void k_dinv(float* __restrict__ deg) {
    int i = blockIdx.x * 256 + threadIdx.x;
    if (i < N_NODES) {
        float d = deg[i];
        deg[i] = (d > 0.0f) ? rsqrtf(d) : 0.0f;
    }
}

__global__ __launch_bounds__(256)
void k_gemm1f(const float* __restrict__ x, const float* __restrict__ W1g,
              float* __restrict__ h1) {
    __shared__ float w1s[D_FEAT * HIDDEN];
    for (int p = threadIdx.x; p < D_FEAT * HIDDEN; p += 256) w1s[p] = W1g[p];
    __syncthreads();
    const int total = N_NODES * HIDDEN;
    for (int t = blockIdx.x * 256 + threadIdx.x; t < total; t += gridDim.x * 256) {
        int i = t >> 4, j = t & 15;
        const float4* xr = (const float4*)(x + (size_t)i * D_FEAT);
        float acc = 0.0f;
#pragma unroll 4
        for (int k4 = 0; k4 < D_FEAT / 4; ++k4) {
            float4 xv = xr[k4];
            int kb = (k4 << 6) + j;
            acc = fmaf(xv.x, w1s[kb],      acc);
            acc = fmaf(xv.y, w1s[kb + 16], acc);
            acc = fmaf(xv.z, w1s[kb + 32], acc);
            acc = fmaf(xv.w, w1s[kb + 48], acc);
        }
        h1[t] = acc;
    }
}

__global__ __launch_bounds__(256)
void k_scatter1(const int* __restrict__ ei, const float* __restrict__ w,
                const int* __restrict__ flag, const float* __restrict__ dinv,
                const float* __restrict__ h1, float* __restrict__ agg1) {
    int t = blockIdx.x * 256 + threadIdx.x;
    if (t >= N_EDGES * HIDDEN) return;
    int e = t >> 4, j = t & 15;
    int is64 = flag[0];
    int r = eidx(ei, is64, e);
    int c = eidx(ei, is64, N_EDGES + e);
    float nrm = dinv[r] * w[e] * dinv[c];
    atomicAdd(&agg1[(size_t)c * HIDDEN + j], nrm * h1[(size_t)r * HIDDEN + j]);
}

__global__ void k_fin1_gemm2(const float* __restrict__ b1, const float* __restrict__ W2,
                             const float* __restrict__ dinv, const float* __restrict__ h1,
                             float* __restrict__ x1, float* __restrict__ h2) {
    int i = blockIdx.x * 256 + threadIdx.x;
    if (i >= N_NODES) return;
    float d2 = dinv[i] * dinv[i];
    float v[HIDDEN];
#pragma unroll
    for (int k = 0; k < HIDDEN; ++k)
        v[k] = x1[(size_t)i * HIDDEN + k] + d2 * h1[(size_t)i * HIDDEN + k] + b1[k];
#pragma unroll
    for (int k = 0; k < HIDDEN; ++k)
        x1[(size_t)i * HIDDEN + k] = v[k];
#pragma unroll
    for (int j = 0; j < NCLS; ++j) {
        float a = 0.0f;
#pragma unroll
        for (int k = 0; k < HIDDEN; ++k) a = fmaf(v[k], W2[k * NCLS + j], a);
        h2[(size_t)i * NCLS + j] = a;
    }
}

__global__ __launch_bounds__(256)
void k_scatter2(const int* __restrict__ ei, const float* __restrict__ w,
                const int* __restrict__ flag, const float* __restrict__ dinv,
                const float* __restrict__ h2, float* __restrict__ agg2) {
    int t = blockIdx.x * 256 + threadIdx.x;
    if (t >= N_EDGES * NCLS) return;
    int e = t / NCLS, j = t - e * NCLS;
    int is64 = flag[0];
    int r = eidx(ei, is64, e);
    int c = eidx(ei, is64, N_EDGES + e);
    float nrm = dinv[r] * w[e] * dinv[c];
    atomicAdd(&agg2[(size_t)c * NCLS + j], nrm * h2[(size_t)r * NCLS + j]);
}

__global__ void k_final(const float* __restrict__ agg2, const float* __restrict__ h2,
                        const float* __restrict__ dinv, const float* __restrict__ b2,
                        float* __restrict__ out) {
    int i = blockIdx.x * 256 + threadIdx.x;
    if (i >= N_NODES) return;
    float d2 = dinv[i] * dinv[i];
    float v[NCLS];
    float m = -1e30f;
#pragma unroll
    for (int j = 0; j < NCLS; ++j) {
        v[j] = agg2[(size_t)i * NCLS + j] + d2 * h2[(size_t)i * NCLS + j] + b2[j];
        m = fmaxf(m, v[j]);
    }
    float s = 0.0f;
#pragma unroll
    for (int j = 0; j < NCLS; ++j) s += __expf(v[j] - m);
    float l = __logf(s);
#pragma unroll
    for (int j = 0; j < NCLS; ++j) out[(size_t)i * NCLS + j] = v[j] - m - l;
}

// ---------- launch ----------

extern "C" void kernel_launch(void* const* d_in, const int* in_sizes, int n_in,
                              void* d_out, int out_size, void* d_ws, size_t ws_size,
                              hipStream_t stream) {
    const float* x  = (const float*)d_in[0];
    const float* W1 = (const float*)d_in[1];
    const float* b1 = (const float*)d_in[2];
    const float* W2 = (const float*)d_in[3];
    const float* b2 = (const float*)d_in[4];
    const float* ew = (const float*)d_in[5];
    const int*   ei = (const int*)d_in[6];

    float* out = (float*)d_out;
    float* lsm = out;                               // [N, 6]
    float* x1  = out + (size_t)N_NODES * NCLS;      // [N, 16]

    const int NB_N = (N_NODES + 255) / 256;         // 391
    const int NB_E = (N_EDGES + 255) / 256;

    float* W    = (float*)d_ws;
    int*   flag = (int*)d_ws;

    // ---- tier-1 layout (4B words) ----
    int*   bcnt    = (int*)(W + 256);        // 783
    int*   bstart  = (int*)(W + 1152);       // 783
    int*   bcursor = (int*)(W + 2048);       // 782
    int*   startA  = (int*)(W + 2944);       // 100001 -> ends 102945
    float* dinvB   = W + 102948;             // 100000 -> ends 202948
    uint2* abuf    = (uint2*)(W + 202948);   // 3.2M uint2 -> ends 6602948; aliased:
    unsigned short* h1b = (unsigned short*)(W + 202948);  // 1.6M bf16 = 800K words
    unsigned short* h2b = (unsigned short*)(W + 1802948); // 800K bf16 = 400K words
    uint2* eperm   = (uint2*)(W + 6602948);  // 3.2M uint2 -> ends 13002948
    const size_t NEED = (size_t)13002948 * 4;       // ~52.0 MB

    if (ws_size >= NEED) {
        hipMemsetAsync(bcnt, 0, (NBUK + 1) * 4, stream);
        k_detect<<<1, 64, 0, stream>>>(ei, flag);
        k_bhist <<<NBLK_A, 256, 0, stream>>>(ei, flag, bcnt);
        k_bscan <<<1, 1024, 0, stream>>>(bcnt, bstart, bcursor);
        k_bscat <<<NBLK_A, 256, 0, stream>>>(ei, ew, flag, bcursor, abuf);
        k_bsort <<<NBUK, 256, 0, stream>>>(bstart, abuf, eperm, startA, dinvB);
        k_gemm1 <<<(N_NODES + 127) / 128, 256, 0, stream>>>(x, W1, h1b);
        k_gather1<<<(N_NODES + 15) / 16, 256, 0, stream>>>(startA, eperm, dinvB, h1b,
                                                           b1, W2, x1, h2b);
        k_gather2<<<(N_NODES + 15) / 16, 256, 0, stream>>>(startA, eperm, dinvB, h2b,
                                                           b2, lsm);
    } else {
        float* deg  = W + 1024;
        float* fh1  = W + 101376;
        float* fh2  = fh1 + (size_t)N_NODES * HIDDEN;
        float* agg2 = fh2 + (size_t)N_NODES * NCLS;
        hipMemsetAsync(x1,   0, (size_t)N_NODES * HIDDEN * sizeof(float), stream);
        hipMemsetAsync(agg2, 0, (size_t)N_NODES * NCLS   * sizeof(float), stream);
        k_detect <<<1, 64, 0, stream>>>(ei, flag);
        k_initdeg<<<NB_N, 256, 0, stream>>>(deg);
        k_degacc <<<NB_E, 256, 0, stream>>>(ei, ew, flag, deg);
        k_dinv   <<<NB_N, 256, 0, stream>>>(deg);
        k_gemm1f <<<2048, 256, 0, stream>>>(x, W1, fh1);
        k_scatter1<<<(N_EDGES * HIDDEN + 255) / 256, 256, 0, stream>>>(ei, ew, flag, deg, fh1, x1);
        k_fin1_gemm2<<<NB_N, 256, 0, stream>>>(b1, W2, deg, fh1, x1, fh2);
        k_scatter2<<<(N_EDGES * NCLS + 255) / 256, 256, 0, stream>>>(ei, ew, flag, deg, fh2, agg2);
        k_final  <<<NB_N, 256, 0, stream>>>(agg2, fh2, deg, b2, lsm);
    }
}